// Round 2
// baseline (1285.094 us; speedup 1.0000x reference)
//
#include <hip/hip_runtime.h>
#include <math.h>

namespace {

constexpr int kNU  = 20000;
constexpr int kNI  = 50000;
constexpr int kH   = 8;
constexpr int kHID = 128;
constexpr int kEUI = 250000;
constexpr int kEIU = 250000;
constexpr int kEUU = 125000;
constexpr int kEU  = kEIU + kEUU;   // edges with user dst (concat order: iu then uu)

__device__ __forceinline__ float geluf(float x) {
  return 0.5f * x * (1.0f + erff(x * 0.7071067811865475f));
}

// ---------------------------------------------------------------------------
// GEMM: C[M,N] = EPI( ACT_IN(A)[M,K] @ B[K,N] + bias[N] )
// B has leading dimension ldb (row stride), N columns used starting at B.
// ACT_IN: 0 identity, 1 exact gelu on A
// EPI:    0 none, 1 relu, 2 sigmoid-gated skip + relu (x_old[M,128], skip scalar)
// Requires K % 64 == 0, N % 64 == 0. M guarded. C/x_old may alias (no restrict).
// ---------------------------------------------------------------------------
template <int ACT_IN, int EPI>
__global__ __launch_bounds__(256) void gemm_kernel(
    const float* __restrict__ A, const float* __restrict__ B,
    const float* __restrict__ bias, float* C,
    int M, int N, int K, int ldb,
    const float* x_old, const float* __restrict__ skip_scalar)
{
  __shared__ float As[64][68];   // transposed: As[k][m], +4 pad
  __shared__ float Bs[64][64];   // Bs[k][n]
  const int tid = threadIdx.x;
  const int tx = tid & 15, ty = tid >> 4;
  const int m0 = blockIdx.y * 64, n0 = blockIdx.x * 64;
  float acc[4][4] = {};
  for (int k0 = 0; k0 < K; k0 += 64) {
    #pragma unroll
    for (int j = 0; j < 4; ++j) {
      int v = tid + j * 256;
      int r = v >> 4, c4 = (v & 15) << 2;
      float4 a = make_float4(0.f, 0.f, 0.f, 0.f);
      if (m0 + r < M)
        a = *reinterpret_cast<const float4*>(A + (size_t)(m0 + r) * K + k0 + c4);
      if (ACT_IN == 1) { a.x = geluf(a.x); a.y = geluf(a.y); a.z = geluf(a.z); a.w = geluf(a.w); }
      As[c4 + 0][r] = a.x; As[c4 + 1][r] = a.y; As[c4 + 2][r] = a.z; As[c4 + 3][r] = a.w;
    }
    #pragma unroll
    for (int j = 0; j < 4; ++j) {
      int v = tid + j * 256;
      int r = v >> 4, c4 = (v & 15) << 2;
      *reinterpret_cast<float4*>(&Bs[r][c4]) =
          *reinterpret_cast<const float4*>(B + (size_t)(k0 + r) * ldb + n0 + c4);
    }
    __syncthreads();
    #pragma unroll
    for (int kk = 0; kk < 64; ++kk) {
      const float4 av = *reinterpret_cast<const float4*>(&As[kk][ty << 2]);
      const float4 bv = *reinterpret_cast<const float4*>(&Bs[kk][tx << 2]);
      const float a4[4] = {av.x, av.y, av.z, av.w};
      const float b4[4] = {bv.x, bv.y, bv.z, bv.w};
      #pragma unroll
      for (int i = 0; i < 4; ++i)
        #pragma unroll
        for (int j = 0; j < 4; ++j)
          acc[i][j] += a4[i] * b4[j];
    }
    __syncthreads();
  }
  float g = 0.f;
  if (EPI == 2) g = 1.f / (1.f + expf(-skip_scalar[0]));
  #pragma unroll
  for (int i = 0; i < 4; ++i) {
    int row = m0 + (ty << 2) + i;
    if (row >= M) continue;
    #pragma unroll
    for (int j = 0; j < 4; ++j) {
      int col = n0 + (tx << 2) + j;
      float v = acc[i][j] + bias[col];
      if (EPI == 1) v = fmaxf(v, 0.f);
      if (EPI == 2) {
        float xo = x_old[(size_t)row * 128 + col];   // read before write (may alias C)
        v = fmaxf(g * v + (1.f - g) * xo, 0.f);
      }
      C[(size_t)row * N + col] = v;
    }
  }
}

// ---------------------------------------------------------------------------
// Build fused relation weights:
//  Wf[idx][c][h*16+f] = scale * sum_d Wsrc[l][c][ofs+h*16+d] * A[l,r,h,d,f]
//  bf[idx][h*16+f]    = scale * sum_d bsrc[l][ofs+h*16+d]    * A[l,r,h,d,f]
//  idx = (l*3+r)*2 + kv ; kv=0 -> A_k with scale p_rel*0.25 (ofs=0, k cols)
//                         kv=1 -> A_v, scale 1 (ofs=256, v cols)
// ---------------------------------------------------------------------------
__global__ __launch_bounds__(256) void build_fused(
    const float* __restrict__ Wku, const float* __restrict__ bku,
    const float* __restrict__ Wki, const float* __restrict__ bki,
    const float* __restrict__ A_k, const float* __restrict__ A_v,
    const float* __restrict__ p_rel,
    float* __restrict__ Wf, float* __restrict__ bf)
{
  const int idx = blockIdx.x;           // 0..11
  const int kv = idx & 1;
  const int lr = idx >> 1;              // l*3 + r
  const int l = lr / 3, r = lr - 3 * l;
  const float* A = (kv ? A_v : A_k) + (size_t)lr * 2048;
  const float* Wsrc;
  const float* bsrc;
  if (r == 1) { Wsrc = Wki + (size_t)l * 128 * 384; bsrc = bki + (size_t)l * 384; }
  else        { Wsrc = Wku + (size_t)l * 128 * 384; bsrc = bku + (size_t)l * 384; }
  const int colofs = kv ? 256 : 0;
  __shared__ float sA[2048];
  for (int i = threadIdx.x; i < 2048; i += 256) sA[i] = A[i];
  __syncthreads();
  float* W = Wf + (size_t)idx * 16384;
  float* b = bf + (size_t)idx * 128;
  for (int t = threadIdx.x; t < 16384; t += 256) {
    const int c = t >> 7, hf = t & 127, h = hf >> 4, f = hf & 15;
    const float scale = kv ? 1.f : p_rel[lr * 8 + h] * 0.25f;
    const float* wrow = Wsrc + (size_t)c * 384 + colofs + h * 16;
    float s = 0.f;
    #pragma unroll
    for (int d = 0; d < 16; ++d) s += wrow[d] * sA[h * 256 + d * 16 + f];
    W[t] = s * scale;
  }
  for (int t = threadIdx.x; t < 128; t += 256) {
    const int h = t >> 4, f = t & 15;
    const float scale = kv ? 1.f : p_rel[lr * 8 + h] * 0.25f;
    float s = 0.f;
    #pragma unroll
    for (int d = 0; d < 16; ++d) s += bsrc[colofs + h * 16 + d] * sA[h * 256 + d * 16 + f];
    b[t] = s * scale;
  }
}

// ---------------------------------------------------------------------------
// CSR build (no hipMemset: explicit zero kernel; cursor aliases counts in scan
// -> no __restrict__ there)
// ---------------------------------------------------------------------------
__global__ void zero2_kernel(int* a, int na, int* b, int nb) {
  int i = blockIdx.x * 256 + threadIdx.x;
  if (i < na) a[i] = 0;
  if (i < nb) b[i] = 0;
}
__global__ void count_item_edges(const int* __restrict__ dst, int* __restrict__ cnt) {
  int e = blockIdx.x * 256 + threadIdx.x;
  if (e < kEUI) atomicAdd(&cnt[dst[e]], 1);
}
__global__ void count_user_edges(const int* __restrict__ dst_iu,
                                 const int* __restrict__ dst_uu, int* __restrict__ cnt) {
  int e = blockIdx.x * 256 + threadIdx.x;
  if (e >= kEU) return;
  int d = (e < kEIU) ? dst_iu[e] : dst_uu[e - kEIU];
  atomicAdd(&cnt[d], 1);
}
__global__ void scatter_item_edges(const int* __restrict__ dst, int* __restrict__ cursor,
                                   int* __restrict__ list) {
  int e = blockIdx.x * 256 + threadIdx.x;
  if (e < kEUI) { int pos = atomicAdd(&cursor[dst[e]], 1); list[pos] = e; }
}
__global__ void scatter_user_edges(const int* __restrict__ dst_iu, const int* __restrict__ dst_uu,
                                   int* __restrict__ cursor, int* __restrict__ list) {
  int e = blockIdx.x * 256 + threadIdx.x;
  if (e >= kEU) return;
  int d = (e < kEIU) ? dst_iu[e] : dst_uu[e - kEIU];
  int pos = atomicAdd(&cursor[d], 1);
  list[pos] = e;
}

// Single-block exclusive scan; cnt_in may alias cursor (same-thread same-index
// read-then-write only) -> NO restrict.
__global__ __launch_bounds__(1024) void scan_kernel(
    const int* cnt_in, int* starts, int* cursor, int n)
{
  __shared__ int wsum[16];
  __shared__ int s_carry;
  const int tid = threadIdx.x;
  const int lane = tid & 63, wv = tid >> 6;
  if (tid == 0) s_carry = 0;
  __syncthreads();
  for (int base = 0; base < n; base += 1024) {
    int i = base + tid;
    int v = (i < n) ? cnt_in[i] : 0;
    int s = v;
    #pragma unroll
    for (int off = 1; off < 64; off <<= 1) {
      int t = __shfl_up(s, off, 64);
      if (lane >= off) s += t;
    }
    if (lane == 63) wsum[wv] = s;
    __syncthreads();
    int woff = 0, total = 0;
    #pragma unroll
    for (int w = 0; w < 16; ++w) { total += wsum[w]; woff += (w < wv) ? wsum[w] : 0; }
    int excl = s_carry + woff + s - v;
    if (i < n) { starts[i] = excl; cursor[i] = excl; }
    __syncthreads();
    if (tid == 0) s_carry += total;
    __syncthreads();
  }
  if (tid == 0) starts[n] = s_carry;
}

// ---------------------------------------------------------------------------
// dst-centric online-softmax aggregation. 16 lanes per (dst, head), lane = f.
// q is dense [n,128].
// ---------------------------------------------------------------------------
__global__ __launch_bounds__(256) void agg_items_kernel(
    const int* __restrict__ starts, const int* __restrict__ list,
    const int* __restrict__ src_arr, const float* __restrict__ q,
    const float* __restrict__ kt, const float* __restrict__ vt,
    float* __restrict__ out, int n_dst)
{
  const int gid = (blockIdx.x * 256 + threadIdx.x) >> 4;
  const int f = threadIdx.x & 15;
  if (gid >= n_dst * kH) return;
  const int dst = gid >> 3, h = gid & 7;
  const float qf = q[(size_t)dst * 128 + h * 16 + f];
  float m = -INFINITY, den = 0.f, acc = 0.f;
  const int s1 = starts[dst + 1];
  for (int idx = starts[dst]; idx < s1; ++idx) {
    const int e = list[idx];
    const int src = src_arr[e];
    const float kv = kt[(size_t)src * 128 + h * 16 + f];
    const float vv = vt[(size_t)src * 128 + h * 16 + f];
    float sc = qf * kv;
    #pragma unroll
    for (int o = 8; o; o >>= 1) sc += __shfl_xor(sc, o, 16);
    const float mn = fmaxf(m, sc);
    const float r = expf(m - mn);     // 0 on first edge (m = -inf)
    const float pe = expf(sc - mn);
    den = den * r + pe;
    acc = acc * r + pe * vv;
    m = mn;
  }
  out[(size_t)dst * 128 + h * 16 + f] = acc / (den + 1e-16f);
}

__global__ __launch_bounds__(256) void agg_users_kernel(
    const int* __restrict__ starts, const int* __restrict__ list,
    const int* __restrict__ src_iu, const int* __restrict__ src_uu,
    const float* __restrict__ q,
    const float* __restrict__ kt1, const float* __restrict__ vt1,
    const float* __restrict__ kt2, const float* __restrict__ vt2,
    float* __restrict__ out, int n_dst)
{
  const int gid = (blockIdx.x * 256 + threadIdx.x) >> 4;
  const int f = threadIdx.x & 15;
  if (gid >= n_dst * kH) return;
  const int dst = gid >> 3, h = gid & 7;
  const float qf = q[(size_t)dst * 128 + h * 16 + f];
  float m = -INFINITY, den = 0.f, acc = 0.f;
  const int s1 = starts[dst + 1];
  for (int idx = starts[dst]; idx < s1; ++idx) {
    const int e = list[idx];
    int src;
    const float* ktp;
    const float* vtp;
    if (e < kEIU) { src = src_iu[e]; ktp = kt1; vtp = vt1; }
    else          { src = src_uu[e - kEIU]; ktp = kt2; vtp = vt2; }
    const float kv = ktp[(size_t)src * 128 + h * 16 + f];
    const float vv = vtp[(size_t)src * 128 + h * 16 + f];
    float sc = qf * kv;
    #pragma unroll
    for (int o = 8; o; o >>= 1) sc += __shfl_xor(sc, o, 16);
    const float mn = fmaxf(m, sc);
    const float r = expf(m - mn);
    const float pe = expf(sc - mn);
    den = den * r + pe;
    acc = acc * r + pe * vv;
    m = mn;
  }
  out[(size_t)dst * 128 + h * 16 + f] = acc / (den + 1e-16f);
}

inline int cdiv(int a, int b) { return (a + b - 1) / b; }

}  // namespace

extern "C" void kernel_launch(void* const* d_in, const int* in_sizes, int n_in,
                              void* d_out, int out_size, void* d_ws, size_t ws_size,
                              hipStream_t stream) {
  // ---- inputs (setup_inputs order) ----
  const float* x_user      = (const float*)d_in[0];
  const float* x_item      = (const float*)d_in[1];
  const int*   src_ui      = (const int*)d_in[2];
  const int*   dst_ui      = (const int*)d_in[3];
  const int*   src_iu      = (const int*)d_in[4];
  const int*   dst_iu      = (const int*)d_in[5];
  const int*   src_uu      = (const int*)d_in[6];
  const int*   dst_uu      = (const int*)d_in[7];
  const float* W_in_user   = (const float*)d_in[8];
  const float* b_in_user   = (const float*)d_in[9];
  const float* W_in_item   = (const float*)d_in[10];
  const float* b_in_item   = (const float*)d_in[11];
  const float* W_kqv_user  = (const float*)d_in[12];
  const float* b_kqv_user  = (const float*)d_in[13];
  const float* W_kqv_item  = (const float*)d_in[14];
  const float* b_kqv_item  = (const float*)d_in[15];
  const float* W_out_user  = (const float*)d_in[16];
  const float* b_out_user  = (const float*)d_in[17];
  const float* W_out_item  = (const float*)d_in[18];
  const float* b_out_item  = (const float*)d_in[19];
  const float* skip_user   = (const float*)d_in[20];
  const float* skip_item   = (const float*)d_in[21];
  const float* A_k         = (const float*)d_in[22];
  const float* A_v         = (const float*)d_in[23];
  const float* p_rel       = (const float*)d_in[24];
  const float* W_lin       = (const float*)d_in[25];
  const float* b_lin       = (const float*)d_in[26];
  float* out = (float*)d_out;
  (void)in_sizes; (void)n_in; (void)out_size; (void)ws_size;

  // ---- workspace carve-up: total ~131.9 MB (< 128 MiB = 134.2 MB) ----
  char* base = (char*)d_ws;
  size_t off = 0;
  auto alloc = [&](size_t nbytes) -> void* {
    void* p = base + off;
    off += (nbytes + 255) & ~(size_t)255;
    return p;
  };
  float* xu   = (float*)alloc((size_t)kNU * 128 * 4);   // persistent; xi contiguous after
  float* xi   = (float*)alloc((size_t)kNI * 128 * 4);
  float* tab  = (float*)alloc((size_t)81920000);        // overlaid per-phase tables
  float* agg_u = (float*)alloc((size_t)kNU * 128 * 4);
  float* Wf   = (float*)alloc((size_t)12 * 16384 * 4);
  float* bf   = (float*)alloc((size_t)12 * 128 * 4);
  int* starts_i = (int*)alloc((size_t)(kNI + 1) * 4);
  int* cursor_i = (int*)alloc((size_t)kNI * 4);
  int* list_i   = (int*)alloc((size_t)kEUI * 4);
  int* starts_u = (int*)alloc((size_t)(kNU + 1) * 4);
  int* cursor_u = (int*)alloc((size_t)kNU * 4);
  int* list_u   = (int*)alloc((size_t)kEU * 4);

  // tab overlay (float offsets). Phase U: q_u, kt1, vt1, kt2, vt2.
  // Phase I: q_i, kt0, vt0, agg_i (reuses space dead after phase U).
  float* q_u  = tab + 0;
  float* kt1  = tab + 2560000;
  float* vt1  = tab + 8960000;
  float* kt2  = tab + 15360000;
  float* vt2  = tab + 17920000;
  float* q_i  = tab + 0;
  float* kt0  = tab + 6400000;
  float* vt0  = tab + 8960000;
  float* agg_i = tab + 11520000;

  // ---- CSR build (edge lists identical across layers -> once per call) ----
  zero2_kernel<<<cdiv(kNI, 256), 256, 0, stream>>>(cursor_i, kNI, cursor_u, kNU);
  count_item_edges<<<cdiv(kEUI, 256), 256, 0, stream>>>(dst_ui, cursor_i);
  count_user_edges<<<cdiv(kEU, 256), 256, 0, stream>>>(dst_iu, dst_uu, cursor_u);
  scan_kernel<<<1, 1024, 0, stream>>>(cursor_i, starts_i, cursor_i, kNI);
  scan_kernel<<<1, 1024, 0, stream>>>(cursor_u, starts_u, cursor_u, kNU);
  scatter_item_edges<<<cdiv(kEUI, 256), 256, 0, stream>>>(dst_ui, cursor_i, list_i);
  scatter_user_edges<<<cdiv(kEU, 256), 256, 0, stream>>>(dst_iu, dst_uu, cursor_u, list_u);

  // ---- fused relation weights (12 tiny matmuls, once per call) ----
  build_fused<<<12, 256, 0, stream>>>(W_kqv_user, b_kqv_user, W_kqv_item, b_kqv_item,
                                      A_k, A_v, p_rel, Wf, bf);

  // ---- input projections (relu) ----
  gemm_kernel<0, 1><<<dim3(2, cdiv(kNU, 64)), 256, 0, stream>>>(
      x_user, W_in_user, b_in_user, xu, kNU, 128, 128, 128, nullptr, nullptr);
  gemm_kernel<0, 1><<<dim3(2, cdiv(kNI, 64)), 256, 0, stream>>>(
      x_item, W_in_item, b_in_item, xi, kNI, 128, 64, 128, nullptr, nullptr);

  for (int l = 0; l < 2; ++l) {
    const float* Wq_u = W_kqv_user + (size_t)l * 128 * 384 + 128;
    const float* bq_u = b_kqv_user + (size_t)l * 384 + 128;
    const float* Wq_i = W_kqv_item + (size_t)l * 128 * 384 + 128;
    const float* bq_i = b_kqv_item + (size_t)l * 384 + 128;
    auto WF = [&](int r, int kv) { return Wf + (size_t)((l * 3 + r) * 2 + kv) * 16384; };
    auto BF = [&](int r, int kv) { return bf + (size_t)((l * 3 + r) * 2 + kv) * 128; };

    // ---- phase U: user-dst aggregation (needs rel 1: item src, rel 2: user src) ----
    gemm_kernel<0, 0><<<dim3(2, cdiv(kNU, 64)), 256, 0, stream>>>(
        xu, Wq_u, bq_u, q_u, kNU, 128, 128, 384, nullptr, nullptr);
    gemm_kernel<0, 0><<<dim3(2, cdiv(kNI, 64)), 256, 0, stream>>>(
        xi, WF(1, 0), BF(1, 0), kt1, kNI, 128, 128, 128, nullptr, nullptr);
    gemm_kernel<0, 0><<<dim3(2, cdiv(kNI, 64)), 256, 0, stream>>>(
        xi, WF(1, 1), BF(1, 1), vt1, kNI, 128, 128, 128, nullptr, nullptr);
    gemm_kernel<0, 0><<<dim3(2, cdiv(kNU, 64)), 256, 0, stream>>>(
        xu, WF(2, 0), BF(2, 0), kt2, kNU, 128, 128, 128, nullptr, nullptr);
    gemm_kernel<0, 0><<<dim3(2, cdiv(kNU, 64)), 256, 0, stream>>>(
        xu, WF(2, 1), BF(2, 1), vt2, kNU, 128, 128, 128, nullptr, nullptr);
    agg_users_kernel<<<cdiv(kNU * 128, 256), 256, 0, stream>>>(
        starts_u, list_u, src_iu, src_uu, q_u, kt1, vt1, kt2, vt2, agg_u, kNU);

    // ---- phase I: item-dst aggregation (rel 0: user src) ----
    gemm_kernel<0, 0><<<dim3(2, cdiv(kNI, 64)), 256, 0, stream>>>(
        xi, Wq_i, bq_i, q_i, kNI, 128, 128, 384, nullptr, nullptr);
    gemm_kernel<0, 0><<<dim3(2, cdiv(kNU, 64)), 256, 0, stream>>>(
        xu, WF(0, 0), BF(0, 0), kt0, kNU, 128, 128, 128, nullptr, nullptr);
    gemm_kernel<0, 0><<<dim3(2, cdiv(kNU, 64)), 256, 0, stream>>>(
        xu, WF(0, 1), BF(0, 1), vt0, kNU, 128, 128, 128, nullptr, nullptr);
    agg_items_kernel<<<cdiv(kNI * 128, 256), 256, 0, stream>>>(
        starts_i, list_i, src_ui, q_i, kt0, vt0, agg_i, kNI);

    // ---- out-proj: gelu -> linear -> sigmoid-gated skip -> relu (in place) ----
    gemm_kernel<1, 2><<<dim3(2, cdiv(kNU, 64)), 256, 0, stream>>>(
        agg_u, W_out_user + (size_t)l * 128 * 128, b_out_user + (size_t)l * 128,
        xu, kNU, 128, 128, 128, xu, skip_user + l);
    gemm_kernel<1, 2><<<dim3(2, cdiv(kNI, 64)), 256, 0, stream>>>(
        agg_i, W_out_item + (size_t)l * 128 * 128, b_out_item + (size_t)l * 128,
        xi, kNI, 128, 128, 128, xi, skip_item + l);
  }

  // ---- final shared linear over concat([xu, xi]) (contiguous in ws) ----
  gemm_kernel<0, 0><<<dim3(1, cdiv(kNU + kNI, 64)), 256, 0, stream>>>(
      xu, W_lin, b_lin, out, kNU + kNI, 64, 128, 64, nullptr, nullptr);
}

// Round 3
// 949.735 us; speedup vs baseline: 1.3531x; 1.3531x over previous
//
#include <hip/hip_runtime.h>
#include <math.h>

namespace {

constexpr int kNU  = 20000;
constexpr int kNI  = 50000;
constexpr int kEUI = 250000;
constexpr int kEIU = 250000;
constexpr int kEUU = 125000;
constexpr int kEU  = kEIU + kEUU;   // edges with user dst (concat order: iu then uu)

__device__ __forceinline__ float geluf(float x) {
  return 0.5f * x * (1.0f + erff(x * 0.7071067811865475f));
}

// ---------------------------------------------------------------------------
// GEMM: C[M,N] = EPI( ACT_IN(A)[M,K] @ B[K,N] + bias[N] )
// B row stride ldb. C row stride = N.
// ACT_IN: 0 identity, 1 exact gelu on A
// EPI:    0 none, 1 relu, 2 sigmoid-gated skip + relu (x_old[M,128], skip scalar)
// Requires K % 64 == 0, N % 64 == 0. M guarded. C/x_old may alias (no restrict).
// ---------------------------------------------------------------------------
template <int ACT_IN, int EPI>
__global__ __launch_bounds__(256) void gemm_kernel(
    const float* __restrict__ A, const float* __restrict__ B,
    const float* __restrict__ bias, float* C,
    int M, int N, int K, int ldb,
    const float* x_old, const float* __restrict__ skip_scalar)
{
  __shared__ float As[64][68];   // transposed: As[k][m], +4 pad
  __shared__ float Bs[64][64];   // Bs[k][n]
  const int tid = threadIdx.x;
  const int tx = tid & 15, ty = tid >> 4;
  const int m0 = blockIdx.y * 64, n0 = blockIdx.x * 64;
  float acc[4][4] = {};
  for (int k0 = 0; k0 < K; k0 += 64) {
    #pragma unroll
    for (int j = 0; j < 4; ++j) {
      int v = tid + j * 256;
      int r = v >> 4, c4 = (v & 15) << 2;
      float4 a = make_float4(0.f, 0.f, 0.f, 0.f);
      if (m0 + r < M)
        a = *reinterpret_cast<const float4*>(A + (size_t)(m0 + r) * K + k0 + c4);
      if (ACT_IN == 1) { a.x = geluf(a.x); a.y = geluf(a.y); a.z = geluf(a.z); a.w = geluf(a.w); }
      As[c4 + 0][r] = a.x; As[c4 + 1][r] = a.y; As[c4 + 2][r] = a.z; As[c4 + 3][r] = a.w;
    }
    #pragma unroll
    for (int j = 0; j < 4; ++j) {
      int v = tid + j * 256;
      int r = v >> 4, c4 = (v & 15) << 2;
      *reinterpret_cast<float4*>(&Bs[r][c4]) =
          *reinterpret_cast<const float4*>(B + (size_t)(k0 + r) * ldb + n0 + c4);
    }
    __syncthreads();
    #pragma unroll
    for (int kk = 0; kk < 64; ++kk) {
      const float4 av = *reinterpret_cast<const float4*>(&As[kk][ty << 2]);
      const float4 bv = *reinterpret_cast<const float4*>(&Bs[kk][tx << 2]);
      const float a4[4] = {av.x, av.y, av.z, av.w};
      const float b4[4] = {bv.x, bv.y, bv.z, bv.w};
      #pragma unroll
      for (int i = 0; i < 4; ++i)
        #pragma unroll
        for (int j = 0; j < 4; ++j)
          acc[i][j] += a4[i] * b4[j];
    }
    __syncthreads();
  }
  float g = 0.f;
  if (EPI == 2) g = 1.f / (1.f + expf(-skip_scalar[0]));
  #pragma unroll
  for (int i = 0; i < 4; ++i) {
    int row = m0 + (ty << 2) + i;
    if (row >= M) continue;
    #pragma unroll
    for (int j = 0; j < 4; ++j) {
      int col = n0 + (tx << 2) + j;
      float v = acc[i][j] + bias[col];
      if (EPI == 1) v = fmaxf(v, 0.f);
      if (EPI == 2) {
        float xo = x_old[(size_t)row * 128 + col];   // read before write (may alias C)
        v = fmaxf(g * v + (1.f - g) * xo, 0.f);
      }
      C[(size_t)row * N + col] = v;
    }
  }
}

// ---------------------------------------------------------------------------
// Build fused projection weights (14 blocks):
//  idx 0..11: (l,r,kv) transform  W' = scale * Wsrc[:, kv-part] @ A[l,r]
//    r==2 -> WuU[l] cols 128+kv*128 (ldb 384)   [user-src tables for user agg]
//    r==1 -> WiU[l] cols kv*128     (ldb 256)   [item-src tables for user agg]
//    r==0 -> WuI[l] cols kv*128     (ldb 256)   [user-src tables for item agg]
//  idx 12,13: copy q_user weights into WuU[l] cols 0..127
//  kv=0: A_k, scale p_rel*0.25 (k cols 0..127); kv=1: A_v, scale 1 (v cols 256..383)
// ---------------------------------------------------------------------------
__global__ __launch_bounds__(256) void build_fused(
    const float* __restrict__ Wku, const float* __restrict__ bku,
    const float* __restrict__ Wki, const float* __restrict__ bki,
    const float* __restrict__ A_k, const float* __restrict__ A_v,
    const float* __restrict__ p_rel,
    float* __restrict__ WuU, float* __restrict__ buU,
    float* __restrict__ WiU, float* __restrict__ biU,
    float* __restrict__ WuI, float* __restrict__ buI)
{
  const int idx = blockIdx.x;
  if (idx >= 12) {
    const int l = idx - 12;
    const float* Wsrc = Wku + (size_t)l * 128 * 384;
    float* W = WuU + (size_t)l * 128 * 384;
    for (int t = threadIdx.x; t < 16384; t += 256) {
      int c = t >> 7, f = t & 127;
      W[(size_t)c * 384 + f] = Wsrc[(size_t)c * 384 + 128 + f];
    }
    for (int t = threadIdx.x; t < 128; t += 256)
      buU[l * 384 + t] = bku[(size_t)l * 384 + 128 + t];
    return;
  }
  const int kv = idx & 1;
  const int lr = idx >> 1;              // l*3 + r
  const int l = lr / 3, r = lr - 3 * l;
  const float* A = (kv ? A_v : A_k) + (size_t)lr * 2048;
  const float* Wsrc;
  const float* bsrc;
  if (r == 1) { Wsrc = Wki + (size_t)l * 128 * 384; bsrc = bki + (size_t)l * 384; }
  else        { Wsrc = Wku + (size_t)l * 128 * 384; bsrc = bku + (size_t)l * 384; }
  const int colsrc = kv ? 256 : 0;
  float* W; float* b; int ldb, colofs;
  if (r == 2)      { W = WuU + (size_t)l * 128 * 384; b = buU + l * 384; ldb = 384; colofs = 128 + kv * 128; }
  else if (r == 1) { W = WiU + (size_t)l * 128 * 256; b = biU + l * 256; ldb = 256; colofs = kv * 128; }
  else             { W = WuI + (size_t)l * 128 * 256; b = buI + l * 256; ldb = 256; colofs = kv * 128; }
  __shared__ float sA[2048];
  for (int i = threadIdx.x; i < 2048; i += 256) sA[i] = A[i];
  __syncthreads();
  for (int t = threadIdx.x; t < 16384; t += 256) {
    const int c = t >> 7, hf = t & 127, h = hf >> 4, f = hf & 15;
    const float scale = kv ? 1.f : p_rel[lr * 8 + h] * 0.25f;
    const float* wrow = Wsrc + (size_t)c * 384 + colsrc + h * 16;
    float s = 0.f;
    #pragma unroll
    for (int d = 0; d < 16; ++d) s += wrow[d] * sA[h * 256 + d * 16 + f];
    W[(size_t)c * ldb + colofs + hf] = s * scale;
  }
  for (int t = threadIdx.x; t < 128; t += 256) {
    const int h = t >> 4, f = t & 15;
    const float scale = kv ? 1.f : p_rel[lr * 8 + h] * 0.25f;
    float s = 0.f;
    #pragma unroll
    for (int d = 0; d < 16; ++d) s += bsrc[colsrc + h * 16 + d] * sA[h * 256 + d * 16 + f];
    b[colofs + t] = s * scale;
  }
}

// ---------------------------------------------------------------------------
// CSR build. list stores SRC id directly; bit31 set -> use tabB (user-src
// tables inside u_all) in agg_users.
// ---------------------------------------------------------------------------
__global__ void zero2_kernel(int* a, int na, int* b, int nb) {
  int i = blockIdx.x * 256 + threadIdx.x;
  if (i < na) a[i] = 0;
  if (i < nb) b[i] = 0;
}
__global__ void count_item_edges(const int* __restrict__ dst, int* __restrict__ cnt) {
  int e = blockIdx.x * 256 + threadIdx.x;
  if (e < kEUI) atomicAdd(&cnt[dst[e]], 1);
}
__global__ void count_user_edges(const int* __restrict__ dst_iu,
                                 const int* __restrict__ dst_uu, int* __restrict__ cnt) {
  int e = blockIdx.x * 256 + threadIdx.x;
  if (e >= kEU) return;
  int d = (e < kEIU) ? dst_iu[e] : dst_uu[e - kEIU];
  atomicAdd(&cnt[d], 1);
}
__global__ void scatter_item_edges(const int* __restrict__ dst, const int* __restrict__ src,
                                   int* __restrict__ cursor, int* __restrict__ list) {
  int e = blockIdx.x * 256 + threadIdx.x;
  if (e < kEUI) { int pos = atomicAdd(&cursor[dst[e]], 1); list[pos] = src[e]; }
}
__global__ void scatter_user_edges(const int* __restrict__ dst_iu, const int* __restrict__ src_iu,
                                   const int* __restrict__ dst_uu, const int* __restrict__ src_uu,
                                   int* __restrict__ cursor, int* __restrict__ list) {
  int e = blockIdx.x * 256 + threadIdx.x;
  if (e >= kEU) return;
  int d, sv;
  if (e < kEIU) { d = dst_iu[e]; sv = src_iu[e]; }
  else          { d = dst_uu[e - kEIU]; sv = src_uu[e - kEIU] | (int)0x80000000; }
  int pos = atomicAdd(&cursor[d], 1);
  list[pos] = sv;
}

// Single-block exclusive scan; cnt_in may alias cursor -> NO restrict.
__global__ __launch_bounds__(1024) void scan_kernel(
    const int* cnt_in, int* starts, int* cursor, int n)
{
  __shared__ int wsum[16];
  __shared__ int s_carry;
  const int tid = threadIdx.x;
  const int lane = tid & 63, wv = tid >> 6;
  if (tid == 0) s_carry = 0;
  __syncthreads();
  for (int base = 0; base < n; base += 1024) {
    int i = base + tid;
    int v = (i < n) ? cnt_in[i] : 0;
    int s = v;
    #pragma unroll
    for (int off = 1; off < 64; off <<= 1) {
      int t = __shfl_up(s, off, 64);
      if (lane >= off) s += t;
    }
    if (lane == 63) wsum[wv] = s;
    __syncthreads();
    int woff = 0, total = 0;
    #pragma unroll
    for (int w = 0; w < 16; ++w) { total += wsum[w]; woff += (w < wv) ? wsum[w] : 0; }
    int excl = s_carry + woff + s - v;
    if (i < n) { starts[i] = excl; cursor[i] = excl; }
    __syncthreads();
    if (tid == 0) s_carry += total;
    __syncthreads();
  }
  if (tid == 0) starts[n] = s_carry;
}

// ---------------------------------------------------------------------------
// Wave-per-dst online-softmax aggregation. 64 lanes = 8 heads x 8 lanes,
// 2 contiguous channels per lane (float2). kt at base+cofs, vt at base+128+cofs.
// list[i] < 0 -> src in tabB (stride strideB, col offset offB); else tabA.
// ---------------------------------------------------------------------------
__global__ __launch_bounds__(256) void agg_wave_kernel(
    const int* __restrict__ starts, const int* __restrict__ list,
    const float* __restrict__ q, int qstride,
    const float* __restrict__ tabA, int strideA,
    const float* __restrict__ tabB, int strideB, int offB,
    float* __restrict__ out, int n_dst)
{
  const int dst = (int)((blockIdx.x * 256 + threadIdx.x) >> 6);
  if (dst >= n_dst) return;
  const int lane = threadIdx.x & 63;
  const int cofs = 2 * lane;            // = h*16 + 2*j
  const float2 qv = *reinterpret_cast<const float2*>(q + (size_t)dst * qstride + cofs);
  float m = -INFINITY, den = 0.f, a0 = 0.f, a1 = 0.f;
  const int i1 = starts[dst + 1];
  int idx = starts[dst];
  int sv_next = (idx < i1) ? list[idx] : 0;
  for (; idx < i1; ++idx) {
    const int sv = sv_next;
    if (idx + 1 < i1) sv_next = list[idx + 1];
    const float* kb;
    if (sv < 0) kb = tabB + (size_t)(sv & 0x7fffffff) * strideB + offB;
    else        kb = tabA + (size_t)sv * strideA;
    const float2 kk = *reinterpret_cast<const float2*>(kb + cofs);
    const float2 vv = *reinterpret_cast<const float2*>(kb + 128 + cofs);
    float p = qv.x * kk.x + qv.y * kk.y;
    p += __shfl_xor(p, 1);
    p += __shfl_xor(p, 2);
    p += __shfl_xor(p, 4);              // sc uniform within 8-lane head group
    const float mn = fmaxf(m, p);
    const float r  = __expf(m - mn);    // 0 on first edge
    const float pe = __expf(p - mn);
    den = den * r + pe;
    a0  = a0 * r + pe * vv.x;
    a1  = a1 * r + pe * vv.y;
    m = mn;
  }
  const float inv = 1.f / (den + 1e-16f);
  *reinterpret_cast<float2*>(out + (size_t)dst * 128 + cofs) = make_float2(a0 * inv, a1 * inv);
}

inline int cdiv(int a, int b) { return (a + b - 1) / b; }

}  // namespace

extern "C" void kernel_launch(void* const* d_in, const int* in_sizes, int n_in,
                              void* d_out, int out_size, void* d_ws, size_t ws_size,
                              hipStream_t stream) {
  // ---- inputs (setup_inputs order) ----
  const float* x_user      = (const float*)d_in[0];
  const float* x_item      = (const float*)d_in[1];
  const int*   src_ui      = (const int*)d_in[2];
  const int*   dst_ui      = (const int*)d_in[3];
  const int*   src_iu      = (const int*)d_in[4];
  const int*   dst_iu      = (const int*)d_in[5];
  const int*   src_uu      = (const int*)d_in[6];
  const int*   dst_uu      = (const int*)d_in[7];
  const float* W_in_user   = (const float*)d_in[8];
  const float* b_in_user   = (const float*)d_in[9];
  const float* W_in_item   = (const float*)d_in[10];
  const float* b_in_item   = (const float*)d_in[11];
  const float* W_kqv_user  = (const float*)d_in[12];
  const float* b_kqv_user  = (const float*)d_in[13];
  const float* W_kqv_item  = (const float*)d_in[14];
  const float* b_kqv_item  = (const float*)d_in[15];
  const float* W_out_user  = (const float*)d_in[16];
  const float* b_out_user  = (const float*)d_in[17];
  const float* W_out_item  = (const float*)d_in[18];
  const float* b_out_item  = (const float*)d_in[19];
  const float* skip_user   = (const float*)d_in[20];
  const float* skip_item   = (const float*)d_in[21];
  const float* A_k         = (const float*)d_in[22];
  const float* A_v         = (const float*)d_in[23];
  const float* p_rel       = (const float*)d_in[24];
  const float* W_lin       = (const float*)d_in[25];
  const float* b_lin       = (const float*)d_in[26];
  float* out = (float*)d_out;
  (void)in_sizes; (void)n_in; (void)out_size; (void)ws_size;

  // ---- workspace carve-up (~131 MB, proven fit) ----
  char* base = (char*)d_ws;
  size_t off = 0;
  auto alloc = [&](size_t nbytes) -> void* {
    void* p = base + off;
    off += (nbytes + 255) & ~(size_t)255;
    return p;
  };
  float* xu    = (float*)alloc((size_t)kNU * 128 * 4);   // persistent; xi contiguous after
  float* xi    = (float*)alloc((size_t)kNI * 128 * 4);
  float* tab   = (float*)alloc((size_t)20480000 * 4);    // 81.92 MB phase-overlaid
  float* agg_u = (float*)alloc((size_t)kNU * 128 * 4);
  float* WuU   = (float*)alloc((size_t)2 * 128 * 384 * 4);
  float* WiU   = (float*)alloc((size_t)2 * 128 * 256 * 4);
  float* WuI   = (float*)alloc((size_t)2 * 128 * 256 * 4);
  float* buU   = (float*)alloc((size_t)2 * 384 * 4);
  float* biU   = (float*)alloc((size_t)2 * 256 * 4);
  float* buI   = (float*)alloc((size_t)2 * 256 * 4);
  int* starts_i = (int*)alloc((size_t)(kNI + 1) * 4);
  int* cursor_i = (int*)alloc((size_t)kNI * 4);
  int* list_i   = (int*)alloc((size_t)kEUI * 4);
  int* starts_u = (int*)alloc((size_t)(kNU + 1) * 4);
  int* cursor_u = (int*)alloc((size_t)kNU * 4);
  int* list_u   = (int*)alloc((size_t)kEU * 4);

  // tab overlay (float offsets):
  // Phase U: u_all [NU x 384] (q|kt2|vt2), i_all [NI x 256] (kt1|vt1)
  // Phase I: u2 [NU x 256] (kt0|vt0), q_i [NI x 128], agg_i [NI x 128]
  float* u_all = tab + 0;          // 7,680,000 floats
  float* i_all = tab + 7680000;    // 12,800,000 floats (end 20,480,000)
  float* u2    = tab + 0;          // 5,120,000
  float* q_i   = tab + 5120000;    // 6,400,000
  float* agg_i = tab + 11520000;   // 6,400,000 (end 17,920,000)

  // ---- CSR build (edge lists identical across layers -> once per call) ----
  zero2_kernel<<<cdiv(kNI, 256), 256, 0, stream>>>(cursor_i, kNI, cursor_u, kNU);
  count_item_edges<<<cdiv(kEUI, 256), 256, 0, stream>>>(dst_ui, cursor_i);
  count_user_edges<<<cdiv(kEU, 256), 256, 0, stream>>>(dst_iu, dst_uu, cursor_u);
  scan_kernel<<<1, 1024, 0, stream>>>(cursor_i, starts_i, cursor_i, kNI);
  scan_kernel<<<1, 1024, 0, stream>>>(cursor_u, starts_u, cursor_u, kNU);
  scatter_item_edges<<<cdiv(kEUI, 256), 256, 0, stream>>>(dst_ui, src_ui, cursor_i, list_i);
  scatter_user_edges<<<cdiv(kEU, 256), 256, 0, stream>>>(dst_iu, src_iu, dst_uu, src_uu,
                                                         cursor_u, list_u);

  // ---- fused projection weights (once per call) ----
  build_fused<<<14, 256, 0, stream>>>(W_kqv_user, b_kqv_user, W_kqv_item, b_kqv_item,
                                      A_k, A_v, p_rel, WuU, buU, WiU, biU, WuI, buI);

  // ---- input projections (relu) ----
  gemm_kernel<0, 1><<<dim3(2, cdiv(kNU, 64)), 256, 0, stream>>>(
      x_user, W_in_user, b_in_user, xu, kNU, 128, 128, 128, nullptr, nullptr);
  gemm_kernel<0, 1><<<dim3(2, cdiv(kNI, 64)), 256, 0, stream>>>(
      x_item, W_in_item, b_in_item, xi, kNI, 128, 64, 128, nullptr, nullptr);

  for (int l = 0; l < 2; ++l) {
    // ---- phase U: q_u|kt2|vt2 from xu, kt1|vt1 from xi, aggregate to users ----
    gemm_kernel<0, 0><<<dim3(6, cdiv(kNU, 64)), 256, 0, stream>>>(
        xu, WuU + (size_t)l * 128 * 384, buU + l * 384, u_all, kNU, 384, 128, 384,
        nullptr, nullptr);
    gemm_kernel<0, 0><<<dim3(4, cdiv(kNI, 64)), 256, 0, stream>>>(
        xi, WiU + (size_t)l * 128 * 256, biU + l * 256, i_all, kNI, 256, 128, 256,
        nullptr, nullptr);
    agg_wave_kernel<<<cdiv(kNU * 64, 256), 256, 0, stream>>>(
        starts_u, list_u, u_all, 384, i_all, 256, u_all, 384, 128, agg_u, kNU);

    // ---- phase I: kt0|vt0 from xu, q_i from xi, aggregate to items ----
    gemm_kernel<0, 0><<<dim3(4, cdiv(kNU, 64)), 256, 0, stream>>>(
        xu, WuI + (size_t)l * 128 * 256, buI + l * 256, u2, kNU, 256, 128, 256,
        nullptr, nullptr);
    gemm_kernel<0, 0><<<dim3(2, cdiv(kNI, 64)), 256, 0, stream>>>(
        xi, W_kqv_item + (size_t)l * 128 * 384 + 128, b_kqv_item + (size_t)l * 384 + 128,
        q_i, kNI, 128, 128, 384, nullptr, nullptr);
    agg_wave_kernel<<<cdiv(kNI * 64, 256), 256, 0, stream>>>(
        starts_i, list_i, q_i, 128, u2, 256, u2, 256, 0, agg_i, kNI);

    // ---- out-proj: gelu -> linear -> sigmoid-gated skip -> relu (in place) ----
    gemm_kernel<1, 2><<<dim3(2, cdiv(kNU, 64)), 256, 0, stream>>>(
        agg_u, W_out_user + (size_t)l * 128 * 128, b_out_user + (size_t)l * 128,
        xu, kNU, 128, 128, 128, xu, skip_user + l);
    gemm_kernel<1, 2><<<dim3(2, cdiv(kNI, 64)), 256, 0, stream>>>(
        agg_i, W_out_item + (size_t)l * 128 * 128, b_out_item + (size_t)l * 128,
        xi, kNI, 128, 128, 128, xi, skip_item + l);
  }

  // ---- final shared linear over concat([xu, xi]) (contiguous in ws) ----
  gemm_kernel<0, 0><<<dim3(1, cdiv(kNU + kNI, 64)), 256, 0, stream>>>(
      xu, W_lin, b_lin, out, kNU + kNI, 64, 128, 64, nullptr, nullptr);
}

// Round 4
// 909.393 us; speedup vs baseline: 1.4131x; 1.0444x over previous
//
#include <hip/hip_runtime.h>
#include <math.h>

namespace {

constexpr int kNU  = 20000;
constexpr int kNI  = 50000;
constexpr int kEUI = 250000;
constexpr int kEIU = 250000;
constexpr int kEUU = 125000;
constexpr int kEU  = kEIU + kEUU;   // edges with user dst (concat order: iu then uu)

typedef __attribute__((ext_vector_type(8))) short bf16x8_t;   // 8 bf16 = 4 VGPRs
typedef __attribute__((ext_vector_type(4))) float f32x4_t;    // MFMA acc

__device__ __forceinline__ float geluf(float x) {
  return 0.5f * x * (1.0f + erff(x * 0.7071067811865475f));
}

// round-to-nearest fp32 -> bf16 hi, residual -> bf16 lo
__device__ __forceinline__ void split_bf16(float x, unsigned short& hi, unsigned short& lo) {
  unsigned u = __float_as_uint(x);
  unsigned h = (u + 0x7FFFu + ((u >> 16) & 1u)) >> 16;
  hi = (unsigned short)h;
  float r = x - __uint_as_float(h << 16);
  unsigned ur = __float_as_uint(r);
  lo = (unsigned short)((ur + 0x7FFFu + ((ur >> 16) & 1u)) >> 16);
}

// ---------------------------------------------------------------------------
// MFMA GEMM (bf16x3 split precision): C[M,N] = EPI( ACT_IN(A)[M,K] @ B[K,N] + bias )
// A fp32 row-major [M][K]. Bt = transposed bf16 weights [2 planes][N][K]
// (hi plane at Bt, lo plane at Bt + N*K). C row stride = N.
// Block tile 128x128, K-step 64. 4 waves, wave tile 64x64 (4x4 frags 16x16x32).
// K % 64 == 0. M, N guarded (N guard only matters when N < 128).
// ---------------------------------------------------------------------------
template <int ACT_IN, int EPI>
__global__ __launch_bounds__(256, 2) void mfma_gemm(
    const float* __restrict__ A, const unsigned short* __restrict__ Bt,
    const float* __restrict__ bias, float* C,
    int M, int N, int K,
    const float* x_old, const float* __restrict__ skip_scalar)
{
  __shared__ unsigned short sA[2][128][72];   // [plane][m][k], row stride 144B
  __shared__ unsigned short sB[2][128][72];   // [plane][n][k]
  const int tid = threadIdx.x;
  const int m0 = blockIdx.y * 128, n0 = blockIdx.x * 128;
  const int lane = tid & 63, w = tid >> 6;
  const int wm = w >> 1, wn = w & 1;          // wave grid 2x2
  const int fr = lane & 15, kg = lane >> 4;
  const unsigned short* Blo = Bt + (size_t)N * K;
  const int r = tid >> 1, seg = tid & 1;      // staging: row 0..127, k-half 0..1
  f32x4_t acc[4][4] = {};

  for (int k0 = 0; k0 < K; k0 += 64) {
    // ---- stage A (fp32 -> hi/lo bf16) ----
    {
      const int arow = m0 + r;
      const bool am = arow < M;
      const float* ap = A + (size_t)arow * K + k0 + seg * 32;
      #pragma unroll
      for (int q = 0; q < 8; ++q) {
        float4 a = am ? *reinterpret_cast<const float4*>(ap + q * 4)
                      : make_float4(0.f, 0.f, 0.f, 0.f);
        if (ACT_IN == 1) { a.x = geluf(a.x); a.y = geluf(a.y); a.z = geluf(a.z); a.w = geluf(a.w); }
        ushort4 h, l;
        split_bf16(a.x, h.x, l.x); split_bf16(a.y, h.y, l.y);
        split_bf16(a.z, h.z, l.z); split_bf16(a.w, h.w, l.w);
        *reinterpret_cast<ushort4*>(&sA[0][r][seg * 32 + q * 4]) = h;
        *reinterpret_cast<ushort4*>(&sA[1][r][seg * 32 + q * 4]) = l;
      }
    }
    // ---- stage B (already bf16 hi/lo, [N][K] layout -> linear copy) ----
    {
      const int brow = n0 + r;
      const bool bm = brow < N;
      const unsigned short* bh = Bt  + (size_t)brow * K + k0 + seg * 32;
      const unsigned short* bl = Blo + (size_t)brow * K + k0 + seg * 32;
      #pragma unroll
      for (int q = 0; q < 4; ++q) {
        uint4 vh = bm ? *reinterpret_cast<const uint4*>(bh + q * 8) : make_uint4(0, 0, 0, 0);
        uint4 vl = bm ? *reinterpret_cast<const uint4*>(bl + q * 8) : make_uint4(0, 0, 0, 0);
        *reinterpret_cast<uint4*>(&sB[0][r][seg * 32 + q * 8]) = vh;
        *reinterpret_cast<uint4*>(&sB[1][r][seg * 32 + q * 8]) = vl;
      }
    }
    __syncthreads();
    #pragma unroll
    for (int ks = 0; ks < 2; ++ks) {
      const int kb = ks * 32 + kg * 8;
      bf16x8_t ah[4], al[4], bh[4], bl[4];
      #pragma unroll
      for (int fm = 0; fm < 4; ++fm) {
        const int row = wm * 64 + fm * 16 + fr;
        ah[fm] = *reinterpret_cast<const bf16x8_t*>(&sA[0][row][kb]);
        al[fm] = *reinterpret_cast<const bf16x8_t*>(&sA[1][row][kb]);
      }
      #pragma unroll
      for (int fn = 0; fn < 4; ++fn) {
        const int row = wn * 64 + fn * 16 + fr;
        bh[fn] = *reinterpret_cast<const bf16x8_t*>(&sB[0][row][kb]);
        bl[fn] = *reinterpret_cast<const bf16x8_t*>(&sB[1][row][kb]);
      }
      #pragma unroll
      for (int fm = 0; fm < 4; ++fm)
        #pragma unroll
        for (int fn = 0; fn < 4; ++fn) {
          acc[fm][fn] = __builtin_amdgcn_mfma_f32_16x16x32_bf16(ah[fm], bh[fn], acc[fm][fn], 0, 0, 0);
          acc[fm][fn] = __builtin_amdgcn_mfma_f32_16x16x32_bf16(ah[fm], bl[fn], acc[fm][fn], 0, 0, 0);
          acc[fm][fn] = __builtin_amdgcn_mfma_f32_16x16x32_bf16(al[fm], bh[fn], acc[fm][fn], 0, 0, 0);
        }
    }
    __syncthreads();
  }

  // ---- epilogue (C/D layout: col = lane&15, row = (lane>>4)*4 + reg) ----
  float g = 0.f;
  if (EPI == 2) g = 1.f / (1.f + __expf(-skip_scalar[0]));
  #pragma unroll
  for (int fn = 0; fn < 4; ++fn) {
    const int col = n0 + wn * 64 + fn * 16 + fr;
    if (col >= N) continue;
    const float bv = bias[col];
    #pragma unroll
    for (int fm = 0; fm < 4; ++fm) {
      #pragma unroll
      for (int i = 0; i < 4; ++i) {
        const int row = m0 + wm * 64 + fm * 16 + kg * 4 + i;
        if (row >= M) continue;
        float v = acc[fm][fn][i] + bv;
        if (EPI == 1) v = fmaxf(v, 0.f);
        if (EPI == 2) {
          float xo = x_old[(size_t)row * 128 + col];   // may alias C; read-then-write
          v = fmaxf(g * v + (1.f - g) * xo, 0.f);
        }
        C[(size_t)row * N + col] = v;
      }
    }
  }
}

// ---------------------------------------------------------------------------
// Weight prep: build ALL GEMM B-operands as transposed bf16 hi/lo planes.
// Blocks 0..11: fused relation transforms (W' = scale * Wsrc[:,part] @ A[l,r])
//   r==2 -> TWuU[l] rows 128+kv*128 (Ntot 384), bias buU
//   r==1 -> TWiU[l] rows kv*128     (Ntot 256), bias biU
//   r==0 -> TWuI[l] rows kv*128     (Ntot 256), bias buI
// Blocks 12,13: q_user -> TWuU[l] rows 0..127 (+ bias copy)
// Blocks 14,15: q_item -> TWqi[l]
// Block  16: W_in_user -> TWinU ; 17: W_in_item -> TWinI
// Blocks 18,19: W_out_user[l] -> TWoutU[l]; 20,21: W_out_item[l] -> TWoutI[l]
// Block  22: W_lin -> TWlin
// ---------------------------------------------------------------------------
__device__ void conv_wt(const float* __restrict__ src, int ld, int cofs,
                        int Kd, int Nd, unsigned short* __restrict__ dst) {
  const int tot = Kd * Nd;
  for (int t = threadIdx.x; t < tot; t += 256) {
    const int n = t / Kd, k = t - n * Kd;
    unsigned short h, l;
    split_bf16(src[(size_t)k * ld + cofs + n], h, l);
    dst[t] = h; dst[tot + t] = l;
  }
}

__global__ __launch_bounds__(256) void build_weights(
    const float* __restrict__ Wku, const float* __restrict__ bku,
    const float* __restrict__ Wki, const float* __restrict__ bki,
    const float* __restrict__ A_k, const float* __restrict__ A_v,
    const float* __restrict__ p_rel,
    const float* __restrict__ W_in_u, const float* __restrict__ W_in_i,
    const float* __restrict__ W_out_u, const float* __restrict__ W_out_i,
    const float* __restrict__ W_lin,
    unsigned short* __restrict__ TWuU, unsigned short* __restrict__ TWiU,
    unsigned short* __restrict__ TWuI, unsigned short* __restrict__ TWqi,
    unsigned short* __restrict__ TWinU, unsigned short* __restrict__ TWinI,
    unsigned short* __restrict__ TWoutU, unsigned short* __restrict__ TWoutI,
    unsigned short* __restrict__ TWlin,
    float* __restrict__ buU, float* __restrict__ biU, float* __restrict__ buI)
{
  const int idx = blockIdx.x;
  if (idx < 12) {
    const int kv = idx & 1;
    const int lr = idx >> 1;              // l*3 + r
    const int l = lr / 3, r = lr - 3 * l;
    const float* A = (kv ? A_v : A_k) + (size_t)lr * 2048;
    const float* Wsrc = (r == 1) ? (Wki + (size_t)l * 128 * 384) : (Wku + (size_t)l * 128 * 384);
    const float* bsrc = (r == 1) ? (bki + (size_t)l * 384) : (bku + (size_t)l * 384);
    const int colsrc = kv ? 256 : 0;
    unsigned short* T; float* b; int colofs, Ntot;
    if (r == 2)      { T = TWuU + (size_t)l * 2 * 384 * 128; b = buU + l * 384; colofs = 128 + kv * 128; Ntot = 384; }
    else if (r == 1) { T = TWiU + (size_t)l * 2 * 256 * 128; b = biU + l * 256; colofs = kv * 128; Ntot = 256; }
    else             { T = TWuI + (size_t)l * 2 * 256 * 128; b = buI + l * 256; colofs = kv * 128; Ntot = 256; }
    __shared__ float sA[2048];
    for (int i = threadIdx.x; i < 2048; i += 256) sA[i] = A[i];
    __syncthreads();
    const int plane = Ntot * 128;
    for (int t = threadIdx.x; t < 16384; t += 256) {
      const int c = t >> 7, hf = t & 127, h = hf >> 4, f = hf & 15;
      const float scale = kv ? 1.f : p_rel[lr * 8 + h] * 0.25f;
      const float* wrow = Wsrc + (size_t)c * 384 + colsrc + h * 16;
      float s = 0.f;
      #pragma unroll
      for (int d = 0; d < 16; ++d) s += wrow[d] * sA[h * 256 + d * 16 + f];
      unsigned short hi, lo;
      split_bf16(s * scale, hi, lo);
      T[(size_t)(colofs + hf) * 128 + c] = hi;
      T[plane + (size_t)(colofs + hf) * 128 + c] = lo;
    }
    for (int t = threadIdx.x; t < 128; t += 256) {
      const int h = t >> 4, f = t & 15;
      const float scale = kv ? 1.f : p_rel[lr * 8 + h] * 0.25f;
      float s = 0.f;
      #pragma unroll
      for (int d = 0; d < 16; ++d) s += bsrc[colsrc + h * 16 + d] * sA[h * 256 + d * 16 + f];
      b[colofs + t] = s * scale;
    }
    return;
  }
  if (idx < 14) {         // q_user -> TWuU rows 0..127 (Ntot=384 interleaved planes)
    const int l = idx - 12;
    const float* src = Wku + (size_t)l * 128 * 384;
    unsigned short* T = TWuU + (size_t)l * 2 * 384 * 128;
    const int plane = 384 * 128;
    for (int t = threadIdx.x; t < 16384; t += 256) {
      const int n = t >> 7, k = t & 127;
      unsigned short h, lo;
      split_bf16(src[(size_t)k * 384 + 128 + n], h, lo);
      T[(size_t)n * 128 + k] = h;
      T[plane + (size_t)n * 128 + k] = lo;
    }
    for (int t = threadIdx.x; t < 128; t += 256)
      buU[l * 384 + t] = bku[(size_t)l * 384 + 128 + t];
    return;
  }
  if (idx < 16) { conv_wt(Wki + (size_t)(idx - 14) * 128 * 384, 384, 128, 128, 128,
                          TWqi + (size_t)(idx - 14) * 2 * 128 * 128); return; }
  if (idx == 16) { conv_wt(W_in_u, 128, 0, 128, 128, TWinU); return; }
  if (idx == 17) { conv_wt(W_in_i, 128, 0, 64, 128, TWinI); return; }
  if (idx < 20) { conv_wt(W_out_u + (size_t)(idx - 18) * 16384, 128, 0, 128, 128,
                          TWoutU + (size_t)(idx - 18) * 2 * 16384); return; }
  if (idx < 22) { conv_wt(W_out_i + (size_t)(idx - 20) * 16384, 128, 0, 128, 128,
                          TWoutI + (size_t)(idx - 20) * 2 * 16384); return; }
  conv_wt(W_lin, 64, 0, 128, 64, TWlin);
}

// ---------------------------------------------------------------------------
// CSR build (merged launches). list stores SRC id; bit31 -> tabB in user agg.
// ---------------------------------------------------------------------------
__global__ void zero2_kernel(int* a, int na, int* b, int nb) {
  int i = blockIdx.x * 256 + threadIdx.x;
  if (i < na) a[i] = 0;
  if (i < nb) b[i] = 0;
}
__global__ void count_all(const int* __restrict__ dst_ui, const int* __restrict__ dst_iu,
                          const int* __restrict__ dst_uu,
                          int* __restrict__ cnt_i, int* __restrict__ cnt_u) {
  int e = blockIdx.x * 256 + threadIdx.x;
  if (e < kEUI) atomicAdd(&cnt_i[dst_ui[e]], 1);
  if (e < kEU) {
    int d = (e < kEIU) ? dst_iu[e] : dst_uu[e - kEIU];
    atomicAdd(&cnt_u[d], 1);
  }
}
__global__ void scatter_all(const int* __restrict__ dst_ui, const int* __restrict__ src_ui,
                            const int* __restrict__ dst_iu, const int* __restrict__ src_iu,
                            const int* __restrict__ dst_uu, const int* __restrict__ src_uu,
                            int* __restrict__ cur_i, int* __restrict__ list_i,
                            int* __restrict__ cur_u, int* __restrict__ list_u) {
  int e = blockIdx.x * 256 + threadIdx.x;
  if (e < kEUI) { int pos = atomicAdd(&cur_i[dst_ui[e]], 1); list_i[pos] = src_ui[e]; }
  if (e < kEU) {
    int d, sv;
    if (e < kEIU) { d = dst_iu[e]; sv = src_iu[e]; }
    else          { d = dst_uu[e - kEIU]; sv = src_uu[e - kEIU] | (int)0x80000000; }
    int pos = atomicAdd(&cur_u[d], 1);
    list_u[pos] = sv;
  }
}

// exclusive scan body; cnt_in may alias cursor -> NO restrict.
__device__ void scan_body(const int* cnt_in, int* starts, int* cursor, int n) {
  __shared__ int wsum[16];
  __shared__ int s_carry;
  const int tid = threadIdx.x;
  const int lane = tid & 63, wv = tid >> 6;
  if (tid == 0) s_carry = 0;
  __syncthreads();
  for (int base = 0; base < n; base += 1024) {
    int i = base + tid;
    int v = (i < n) ? cnt_in[i] : 0;
    int s = v;
    #pragma unroll
    for (int off = 1; off < 64; off <<= 1) {
      int t = __shfl_up(s, off, 64);
      if (lane >= off) s += t;
    }
    if (lane == 63) wsum[wv] = s;
    __syncthreads();
    int woff = 0, total = 0;
    #pragma unroll
    for (int w = 0; w < 16; ++w) { total += wsum[w]; woff += (w < wv) ? wsum[w] : 0; }
    int excl = s_carry + woff + s - v;
    if (i < n) { starts[i] = excl; cursor[i] = excl; }
    __syncthreads();
    if (tid == 0) s_carry += total;
    __syncthreads();
  }
  if (tid == 0) starts[n] = s_carry;
}
__global__ __launch_bounds__(1024) void scan2_kernel(
    int* cnt_i, int* starts_i, int n_i, int* cnt_u, int* starts_u, int n_u) {
  if (blockIdx.x == 0) scan_body(cnt_i, starts_i, cnt_i, n_i);
  else                 scan_body(cnt_u, starts_u, cnt_u, n_u);
}

// ---------------------------------------------------------------------------
// Wave-per-dst online-softmax aggregation. 64 lanes = 8 heads x 8 lanes,
// 2 contiguous channels per lane (float2). kt at base+cofs, vt at base+128+cofs.
// list[i] < 0 -> src in tabB (stride strideB, col offset offB); else tabA.
// ---------------------------------------------------------------------------
__global__ __launch_bounds__(256) void agg_wave_kernel(
    const int* __restrict__ starts, const int* __restrict__ list,
    const float* __restrict__ q, int qstride,
    const float* __restrict__ tabA, int strideA,
    const float* __restrict__ tabB, int strideB, int offB,
    float* __restrict__ out, int n_dst)
{
  const int dst = (int)((blockIdx.x * 256 + threadIdx.x) >> 6);
  if (dst >= n_dst) return;
  const int lane = threadIdx.x & 63;
  const int cofs = 2 * lane;            // = h*16 + 2*j
  const float2 qv = *reinterpret_cast<const float2*>(q + (size_t)dst * qstride + cofs);
  float m = -INFINITY, den = 0.f, a0 = 0.f, a1 = 0.f;
  const int i1 = starts[dst + 1];
  int idx = starts[dst];
  int sv_next = (idx < i1) ? list[idx] : 0;
  for (; idx < i1; ++idx) {
    const int sv = sv_next;
    if (idx + 1 < i1) sv_next = list[idx + 1];
    const float* kb;
    if (sv < 0) kb = tabB + (size_t)(sv & 0x7fffffff) * strideB + offB;
    else        kb = tabA + (size_t)sv * strideA;
    const float2 kk = *reinterpret_cast<const float2*>(kb + cofs);
    const float2 vv = *reinterpret_cast<const float2*>(kb + 128 + cofs);
    float p = qv.x * kk.x + qv.y * kk.y;
    p += __shfl_xor(p, 1);
    p += __shfl_xor(p, 2);
    p += __shfl_xor(p, 4);              // score uniform within 8-lane head group
    const float mn = fmaxf(m, p);
    const float r  = __expf(m - mn);    // 0 on first edge
    const float pe = __expf(p - mn);
    den = den * r + pe;
    a0  = a0 * r + pe * vv.x;
    a1  = a1 * r + pe * vv.y;
    m = mn;
  }
  const float inv = 1.f / (den + 1e-16f);
  *reinterpret_cast<float2*>(out + (size_t)dst * 128 + cofs) = make_float2(a0 * inv, a1 * inv);
}

inline int cdiv(int a, int b) { return (a + b - 1) / b; }

}  // namespace

extern "C" void kernel_launch(void* const* d_in, const int* in_sizes, int n_in,
                              void* d_out, int out_size, void* d_ws, size_t ws_size,
                              hipStream_t stream) {
  // ---- inputs (setup_inputs order) ----
  const float* x_user      = (const float*)d_in[0];
  const float* x_item      = (const float*)d_in[1];
  const int*   src_ui      = (const int*)d_in[2];
  const int*   dst_ui      = (const int*)d_in[3];
  const int*   src_iu      = (const int*)d_in[4];
  const int*   dst_iu      = (const int*)d_in[5];
  const int*   src_uu      = (const int*)d_in[6];
  const int*   dst_uu      = (const int*)d_in[7];
  const float* W_in_user   = (const float*)d_in[8];
  const float* b_in_user   = (const float*)d_in[9];
  const float* W_in_item   = (const float*)d_in[10];
  const float* b_in_item   = (const float*)d_in[11];
  const float* W_kqv_user  = (const float*)d_in[12];
  const float* b_kqv_user  = (const float*)d_in[13];
  const float* W_kqv_item  = (const float*)d_in[14];
  const float* b_kqv_item  = (const float*)d_in[15];
  const float* W_out_user  = (const float*)d_in[16];
  const float* b_out_user  = (const float*)d_in[17];
  const float* W_out_item  = (const float*)d_in[18];
  const float* b_out_item  = (const float*)d_in[19];
  const float* skip_user   = (const float*)d_in[20];
  const float* skip_item   = (const float*)d_in[21];
  const float* A_k         = (const float*)d_in[22];
  const float* A_v         = (const float*)d_in[23];
  const float* p_rel       = (const float*)d_in[24];
  const float* W_lin       = (const float*)d_in[25];
  const float* b_lin       = (const float*)d_in[26];
  float* out = (float*)d_out;
  (void)in_sizes; (void)n_in; (void)out_size; (void)ws_size;

  // ---- workspace carve-up (~124 MB) ----
  char* base = (char*)d_ws;
  size_t off = 0;
  auto alloc = [&](size_t nbytes) -> void* {
    void* p = base + off;
    off += (nbytes + 255) & ~(size_t)255;
    return p;
  };
  float* xu    = (float*)alloc((size_t)kNU * 128 * 4);   // persistent; xi contiguous after
  float* xi    = (float*)alloc((size_t)kNI * 128 * 4);
  float* tab   = (float*)alloc((size_t)20480000 * 4);    // 81.92 MB phase-overlaid
  float* agg_u = (float*)alloc((size_t)kNU * 128 * 4);
  unsigned short* TWuU   = (unsigned short*)alloc((size_t)2 * 2 * 384 * 128 * 2);
  unsigned short* TWiU   = (unsigned short*)alloc((size_t)2 * 2 * 256 * 128 * 2);
  unsigned short* TWuI   = (unsigned short*)alloc((size_t)2 * 2 * 256 * 128 * 2);
  unsigned short* TWqi   = (unsigned short*)alloc((size_t)2 * 2 * 128 * 128 * 2);
  unsigned short* TWinU  = (unsigned short*)alloc((size_t)2 * 128 * 128 * 2);
  unsigned short* TWinI  = (unsigned short*)alloc((size_t)2 * 128 * 64 * 2);
  unsigned short* TWoutU = (unsigned short*)alloc((size_t)2 * 2 * 128 * 128 * 2);
  unsigned short* TWoutI = (unsigned short*)alloc((size_t)2 * 2 * 128 * 128 * 2);
  unsigned short* TWlin  = (unsigned short*)alloc((size_t)2 * 64 * 128 * 2);
  float* buU   = (float*)alloc((size_t)2 * 384 * 4);
  float* biU   = (float*)alloc((size_t)2 * 256 * 4);
  float* buI   = (float*)alloc((size_t)2 * 256 * 4);
  int* starts_i = (int*)alloc((size_t)(kNI + 1) * 4);
  int* cursor_i = (int*)alloc((size_t)kNI * 4);
  int* list_i   = (int*)alloc((size_t)kEUI * 4);
  int* starts_u = (int*)alloc((size_t)(kNU + 1) * 4);
  int* cursor_u = (int*)alloc((size_t)kNU * 4);
  int* list_u   = (int*)alloc((size_t)kEU * 4);

  // tab overlay (float offsets):
  // Phase U: u_all [NU x 384] (q|kt2|vt2), i_all [NI x 256] (kt1|vt1)
  // Phase I: u2 [NU x 256] (kt0|vt0), q_i [NI x 128], agg_i [NI x 128]
  float* u_all = tab + 0;
  float* i_all = tab + 7680000;
  float* u2    = tab + 0;
  float* q_i   = tab + 5120000;
  float* agg_i = tab + 11520000;

  // ---- CSR build (edge lists identical across layers -> once per call) ----
  zero2_kernel<<<cdiv(kNI, 256), 256, 0, stream>>>(cursor_i, kNI, cursor_u, kNU);
  count_all<<<cdiv(kEU, 256), 256, 0, stream>>>(dst_ui, dst_iu, dst_uu, cursor_i, cursor_u);
  scan2_kernel<<<2, 1024, 0, stream>>>(cursor_i, starts_i, kNI, cursor_u, starts_u, kNU);
  scatter_all<<<cdiv(kEU, 256), 256, 0, stream>>>(dst_ui, src_ui, dst_iu, src_iu,
                                                  dst_uu, src_uu, cursor_i, list_i,
                                                  cursor_u, list_u);

  // ---- weight prep: fused transforms + transpose + bf16 hi/lo split ----
  build_weights<<<23, 256, 0, stream>>>(
      W_kqv_user, b_kqv_user, W_kqv_item, b_kqv_item, A_k, A_v, p_rel,
      W_in_user, W_in_item, W_out_user, W_out_item, W_lin,
      TWuU, TWiU, TWuI, TWqi, TWinU, TWinI, TWoutU, TWoutI, TWlin,
      buU, biU, buI);

  // ---- input projections (relu) ----
  mfma_gemm<0, 1><<<dim3(1, cdiv(kNU, 128)), 256, 0, stream>>>(
      x_user, TWinU, b_in_user, xu, kNU, 128, 128, nullptr, nullptr);
  mfma_gemm<0, 1><<<dim3(1, cdiv(kNI, 128)), 256, 0, stream>>>(
      x_item, TWinI, b_in_item, xi, kNI, 128, 64, nullptr, nullptr);

  for (int l = 0; l < 2; ++l) {
    // ---- phase U: q_u|kt2|vt2 from xu, kt1|vt1 from xi, aggregate to users ----
    mfma_gemm<0, 0><<<dim3(3, cdiv(kNU, 128)), 256, 0, stream>>>(
        xu, TWuU + (size_t)l * 2 * 384 * 128, buU + l * 384, u_all, kNU, 384, 128,
        nullptr, nullptr);
    mfma_gemm<0, 0><<<dim3(2, cdiv(kNI, 128)), 256, 0, stream>>>(
        xi, TWiU + (size_t)l * 2 * 256 * 128, biU + l * 256, i_all, kNI, 256, 128,
        nullptr, nullptr);
    agg_wave_kernel<<<cdiv(kNU * 64, 256), 256, 0, stream>>>(
        starts_u, list_u, u_all, 384, i_all, 256, u_all, 384, 128, agg_u, kNU);

    // ---- phase I: kt0|vt0 from xu, q_i from xi, aggregate to items ----
    mfma_gemm<0, 0><<<dim3(2, cdiv(kNU, 128)), 256, 0, stream>>>(
        xu, TWuI + (size_t)l * 2 * 256 * 128, buI + l * 256, u2, kNU, 256, 128,
        nullptr, nullptr);
    mfma_gemm<0, 0><<<dim3(1, cdiv(kNI, 128)), 256, 0, stream>>>(
        xi, TWqi + (size_t)l * 2 * 128 * 128, b_kqv_item + (size_t)l * 384 + 128,
        q_i, kNI, 128, 128, nullptr, nullptr);
    agg_wave_kernel<<<cdiv(kNI * 64, 256), 256, 0, stream>>>(
        starts_i, list_i, q_i, 128, u2, 256, u2, 256, 0, agg_i, kNI);

    // ---- out-proj: gelu -> linear -> sigmoid-gated skip -> relu (in place) ----
    mfma_gemm<1, 2><<<dim3(1, cdiv(kNU, 128)), 256, 0, stream>>>(
        agg_u, TWoutU + (size_t)l * 2 * 128 * 128, b_out_user + (size_t)l * 128,
        xu, kNU, 128, 128, xu, skip_user + l);
    mfma_gemm<1, 2><<<dim3(1, cdiv(kNI, 128)), 256, 0, stream>>>(
        agg_i, TWoutI + (size_t)l * 2 * 128 * 128, b_out_item + (size_t)l * 128,
        xi, kNI, 128, 128, xi, skip_item + l);
  }

  // ---- final shared linear over concat([xu, xi]) (contiguous in ws) ----
  mfma_gemm<0, 0><<<dim3(1, cdiv(kNU + kNI, 128)), 256, 0, stream>>>(
      xu, TWlin, b_lin, out, kNU + kNI, 64, 128, nullptr, nullptr);
}

// Round 6
// 875.943 us; speedup vs baseline: 1.4671x; 1.0382x over previous
//
#include <hip/hip_runtime.h>
#include <math.h>

namespace {

constexpr int kNU  = 20000;
constexpr int kNI  = 50000;
constexpr int kEUI = 250000;
constexpr int kEIU = 250000;
constexpr int kEUU = 125000;
constexpr int kEU  = kEIU + kEUU;   // edges with user dst (concat order: iu then uu)

typedef __attribute__((ext_vector_type(8))) short bf16x8_t;   // 8 bf16 = 4 VGPRs
typedef __attribute__((ext_vector_type(4))) float f32x4_t;    // MFMA acc

__device__ __forceinline__ float geluf(float x) {
  return 0.5f * x * (1.0f + erff(x * 0.7071067811865475f));
}

// round-to-nearest fp32 -> bf16 hi, residual -> bf16 lo
__device__ __forceinline__ void split_bf16(float x, unsigned short& hi, unsigned short& lo) {
  unsigned u = __float_as_uint(x);
  unsigned h = (u + 0x7FFFu + ((u >> 16) & 1u)) >> 16;
  hi = (unsigned short)h;
  float r = x - __uint_as_float(h << 16);
  unsigned ur = __float_as_uint(r);
  lo = (unsigned short)((ur + 0x7FFFu + ((ur >> 16) & 1u)) >> 16);
}

// ---------------------------------------------------------------------------
// MFMA GEMM (bf16x3 split precision): C[M,N] = EPI( ACT_IN(A)[M,K] @ B[K,N] + bias )
// A fp32 row-major [M][K]. Bt = transposed bf16 weights [2 planes][N][K]
// (hi plane at Bt, lo plane at Bt + N*K). C row stride = N.
// Block tile 128x128, K-step 64. 4 waves, wave tile 64x64 (4x4 frags 16x16x32).
// K % 64 == 0. M, N guarded.  [verbatim round-4 kernel — passed twice]
// ---------------------------------------------------------------------------
template <int ACT_IN, int EPI>
__global__ __launch_bounds__(256, 2) void mfma_gemm(
    const float* __restrict__ A, const unsigned short* __restrict__ Bt,
    const float* __restrict__ bias, float* C,
    int M, int N, int K,
    const float* x_old, const float* __restrict__ skip_scalar)
{
  __shared__ unsigned short sA[2][128][72];   // [plane][m][k]
  __shared__ unsigned short sB[2][128][72];   // [plane][n][k]
  const int tid = threadIdx.x;
  const int m0 = blockIdx.y * 128, n0 = blockIdx.x * 128;
  const int lane = tid & 63, w = tid >> 6;
  const int wm = w >> 1, wn = w & 1;          // wave grid 2x2
  const int fr = lane & 15, kg = lane >> 4;
  const unsigned short* Blo = Bt + (size_t)N * K;
  const int r = tid >> 1, seg = tid & 1;      // staging: row 0..127, k-half 0..1
  f32x4_t acc[4][4] = {};

  for (int k0 = 0; k0 < K; k0 += 64) {
    // ---- stage A (fp32 -> hi/lo bf16) ----
    {
      const int arow = m0 + r;
      const bool am = arow < M;
      const float* ap = A + (size_t)arow * K + k0 + seg * 32;
      #pragma unroll
      for (int q = 0; q < 8; ++q) {
        float4 a = am ? *reinterpret_cast<const float4*>(ap + q * 4)
                      : make_float4(0.f, 0.f, 0.f, 0.f);
        if (ACT_IN == 1) { a.x = geluf(a.x); a.y = geluf(a.y); a.z = geluf(a.z); a.w = geluf(a.w); }
        ushort4 h, l;
        split_bf16(a.x, h.x, l.x); split_bf16(a.y, h.y, l.y);
        split_bf16(a.z, h.z, l.z); split_bf16(a.w, h.w, l.w);
        *reinterpret_cast<ushort4*>(&sA[0][r][seg * 32 + q * 4]) = h;
        *reinterpret_cast<ushort4*>(&sA[1][r][seg * 32 + q * 4]) = l;
      }
    }
    // ---- stage B (already bf16 hi/lo, [N][K] layout -> linear copy) ----
    {
      const int brow = n0 + r;
      const bool bm = brow < N;
      const unsigned short* bh = Bt  + (size_t)brow * K + k0 + seg * 32;
      const unsigned short* bl = Blo + (size_t)brow * K + k0 + seg * 32;
      #pragma unroll
      for (int q = 0; q < 4; ++q) {
        uint4 vh = bm ? *reinterpret_cast<const uint4*>(bh + q * 8) : make_uint4(0, 0, 0, 0);
        uint4 vl = bm ? *reinterpret_cast<const uint4*>(bl + q * 8) : make_uint4(0, 0, 0, 0);
        *reinterpret_cast<uint4*>(&sB[0][r][seg * 32 + q * 8]) = vh;
        *reinterpret_cast<uint4*>(&sB[1][r][seg * 32 + q * 8]) = vl;
      }
    }
    __syncthreads();
    #pragma unroll
    for (int ks = 0; ks < 2; ++ks) {
      const int kb = ks * 32 + kg * 8;
      bf16x8_t ah[4], al[4], bh[4], bl[4];
      #pragma unroll
      for (int fm = 0; fm < 4; ++fm) {
        const int row = wm * 64 + fm * 16 + fr;
        ah[fm] = *reinterpret_cast<const bf16x8_t*>(&sA[0][row][kb]);
        al[fm] = *reinterpret_cast<const bf16x8_t*>(&sA[1][row][kb]);
      }
      #pragma unroll
      for (int fn = 0; fn < 4; ++fn) {
        const int row = wn * 64 + fn * 16 + fr;
        bh[fn] = *reinterpret_cast<const bf16x8_t*>(&sB[0][row][kb]);
        bl[fn] = *reinterpret_cast<const bf16x8_t*>(&sB[1][row][kb]);
      }
      #pragma unroll
      for (int fm = 0; fm < 4; ++fm)
        #pragma unroll
        for (int fn = 0; fn < 4; ++fn) {
          acc[fm][fn] = __builtin_amdgcn_mfma_f32_16x16x32_bf16(ah[fm], bh[fn], acc[fm][fn], 0, 0, 0);
          acc[fm][fn] = __builtin_amdgcn_mfma_f32_16x16x32_bf16(ah[fm], bl[fn], acc[fm][fn], 0, 0, 0);
          acc[fm][fn] = __builtin_amdgcn_mfma_f32_16x16x32_bf16(al[fm], bh[fn], acc[fm][fn], 0, 0, 0);
        }
    }
    __syncthreads();
  }

  // ---- epilogue (C/D layout: col = lane&15, row = (lane>>4)*4 + reg) ----
  float g = 0.f;
  if (EPI == 2) g = 1.f / (1.f + __expf(-skip_scalar[0]));
  #pragma unroll
  for (int fn = 0; fn < 4; ++fn) {
    const int col = n0 + wn * 64 + fn * 16 + fr;
    if (col >= N) continue;
    const float bv = bias[col];
    #pragma unroll
    for (int fm = 0; fm < 4; ++fm) {
      #pragma unroll
      for (int i = 0; i < 4; ++i) {
        const int row = m0 + wm * 64 + fm * 16 + kg * 4 + i;
        if (row >= M) continue;
        float v = acc[fm][fn][i] + bv;
        if (EPI == 1) v = fmaxf(v, 0.f);
        if (EPI == 2) {
          float xo = x_old[(size_t)row * 128 + col];   // read-then-write (may alias C)
          v = fmaxf(g * v + (1.f - g) * xo, 0.f);
        }
        C[(size_t)row * N + col] = v;
      }
    }
  }
}

// ---------------------------------------------------------------------------
// Weight prep (sliced: grid = 23 ops x 16 slices).
// Ops 0..11: fused relation transforms; 12,13: q_user copy; 14,15: q_item;
// 16/17: W_in_user/item; 18..21: W_out; 22: W_lin.
// ---------------------------------------------------------------------------
constexpr int kSlices = 16;

__device__ void conv_wt(const float* __restrict__ src, int ld, int cofs,
                        int Kd, int Nd, unsigned short* __restrict__ dst, int slice) {
  const int tot = Kd * Nd;
  for (int t = slice * 256 + threadIdx.x; t < tot; t += kSlices * 256) {
    const int n = t / Kd, k = t - n * Kd;
    unsigned short h, l;
    split_bf16(src[(size_t)k * ld + cofs + n], h, l);
    dst[t] = h; dst[tot + t] = l;
  }
}

__global__ __launch_bounds__(256) void build_weights(
    const float* __restrict__ Wku, const float* __restrict__ bku,
    const float* __restrict__ Wki, const float* __restrict__ bki,
    const float* __restrict__ A_k, const float* __restrict__ A_v,
    const float* __restrict__ p_rel,
    const float* __restrict__ W_in_u, const float* __restrict__ W_in_i,
    const float* __restrict__ W_out_u, const float* __restrict__ W_out_i,
    const float* __restrict__ W_lin,
    unsigned short* __restrict__ TWuU, unsigned short* __restrict__ TWiU,
    unsigned short* __restrict__ TWuI, unsigned short* __restrict__ TWqi,
    unsigned short* __restrict__ TWinU, unsigned short* __restrict__ TWinI,
    unsigned short* __restrict__ TWoutU, unsigned short* __restrict__ TWoutI,
    unsigned short* __restrict__ TWlin,
    float* __restrict__ buU, float* __restrict__ biU, float* __restrict__ buI)
{
  const int idx = blockIdx.x >> 4;      // op id 0..22
  const int slice = blockIdx.x & 15;
  if (idx < 12) {
    const int kv = idx & 1;
    const int lr = idx >> 1;            // l*3 + r
    const int l = lr / 3, r = lr - 3 * l;
    const float* A = (kv ? A_v : A_k) + (size_t)lr * 2048;
    const float* Wsrc = (r == 1) ? (Wki + (size_t)l * 128 * 384) : (Wku + (size_t)l * 128 * 384);
    const float* bsrc = (r == 1) ? (bki + (size_t)l * 384) : (bku + (size_t)l * 384);
    const int colsrc = kv ? 256 : 0;
    unsigned short* T; float* b; int colofs, Ntot;
    if (r == 2)      { T = TWuU + (size_t)l * 2 * 384 * 128; b = buU + l * 384; colofs = 128 + kv * 128; Ntot = 384; }
    else if (r == 1) { T = TWiU + (size_t)l * 2 * 256 * 128; b = biU + l * 256; colofs = kv * 128; Ntot = 256; }
    else             { T = TWuI + (size_t)l * 2 * 256 * 128; b = buI + l * 256; colofs = kv * 128; Ntot = 256; }
    __shared__ float sA[2048];
    for (int i = threadIdx.x; i < 2048; i += 256) sA[i] = A[i];
    __syncthreads();
    const int plane = Ntot * 128;
    for (int t = slice * 256 + threadIdx.x; t < 16384; t += kSlices * 256) {
      const int c = t >> 7, hf = t & 127, h = hf >> 4, f = hf & 15;
      const float scale = kv ? 1.f : p_rel[lr * 8 + h] * 0.25f;
      const float* wrow = Wsrc + (size_t)c * 384 + colsrc + h * 16;
      float s = 0.f;
      #pragma unroll
      for (int d = 0; d < 16; ++d) s += wrow[d] * sA[h * 256 + d * 16 + f];
      unsigned short hi, lo;
      split_bf16(s * scale, hi, lo);
      T[(size_t)(colofs + hf) * 128 + c] = hi;
      T[plane + (size_t)(colofs + hf) * 128 + c] = lo;
    }
    if (slice == 0) {
      for (int t = threadIdx.x; t < 128; t += 256) {
        const int h = t >> 4, f = t & 15;
        const float scale = kv ? 1.f : p_rel[lr * 8 + h] * 0.25f;
        float s = 0.f;
        #pragma unroll
        for (int d = 0; d < 16; ++d) s += bsrc[colsrc + h * 16 + d] * sA[h * 256 + d * 16 + f];
        b[colofs + t] = s * scale;
      }
    }
    return;
  }
  if (idx < 14) {         // q_user -> TWuU rows 0..127
    const int l = idx - 12;
    const float* src = Wku + (size_t)l * 128 * 384;
    unsigned short* T = TWuU + (size_t)l * 2 * 384 * 128;
    const int plane = 384 * 128;
    for (int t = slice * 256 + threadIdx.x; t < 16384; t += kSlices * 256) {
      const int n = t >> 7, k = t & 127;
      unsigned short h, lo;
      split_bf16(src[(size_t)k * 384 + 128 + n], h, lo);
      T[(size_t)n * 128 + k] = h;
      T[plane + (size_t)n * 128 + k] = lo;
    }
    if (slice == 0)
      for (int t = threadIdx.x; t < 128; t += 256)
        buU[l * 384 + t] = bku[(size_t)l * 384 + 128 + t];
    return;
  }
  if (idx < 16) { conv_wt(Wki + (size_t)(idx - 14) * 128 * 384, 384, 128, 128, 128,
                          TWqi + (size_t)(idx - 14) * 2 * 128 * 128, slice); return; }
  if (idx == 16) { conv_wt(W_in_u, 128, 0, 128, 128, TWinU, slice); return; }
  if (idx == 17) { conv_wt(W_in_i, 128, 0, 64, 128, TWinI, slice); return; }
  if (idx < 20) { conv_wt(W_out_u + (size_t)(idx - 18) * 16384, 128, 0, 128, 128,
                          TWoutU + (size_t)(idx - 18) * 2 * 16384, slice); return; }
  if (idx < 22) { conv_wt(W_out_i + (size_t)(idx - 20) * 16384, 128, 0, 128, 128,
                          TWoutI + (size_t)(idx - 20) * 2 * 16384, slice); return; }
  conv_wt(W_lin, 64, 0, 128, 64, TWlin, slice);
}

// ---------------------------------------------------------------------------
// CSR build. list stores SRC id; bit31 -> tabB in user agg.
// ---------------------------------------------------------------------------
__global__ void zero2_kernel(int* a, int na, int* b, int nb) {
  int i = blockIdx.x * 256 + threadIdx.x;
  if (i < na) a[i] = 0;
  if (i < nb) b[i] = 0;
}
__global__ void count_all(const int* __restrict__ dst_ui, const int* __restrict__ dst_iu,
                          const int* __restrict__ dst_uu,
                          int* __restrict__ cnt_i, int* __restrict__ cnt_u) {
  int e = blockIdx.x * 256 + threadIdx.x;
  if (e < kEUI) atomicAdd(&cnt_i[dst_ui[e]], 1);
  if (e < kEU) {
    int d = (e < kEIU) ? dst_iu[e] : dst_uu[e - kEIU];
    atomicAdd(&cnt_u[d], 1);
  }
}
__global__ void scatter_all(const int* __restrict__ dst_ui, const int* __restrict__ src_ui,
                            const int* __restrict__ dst_iu, const int* __restrict__ src_iu,
                            const int* __restrict__ dst_uu, const int* __restrict__ src_uu,
                            int* __restrict__ cur_i, int* __restrict__ list_i,
                            int* __restrict__ cur_u, int* __restrict__ list_u) {
  int e = blockIdx.x * 256 + threadIdx.x;
  if (e < kEUI) { int pos = atomicAdd(&cur_i[dst_ui[e]], 1); list_i[pos] = src_ui[e]; }
  if (e < kEU) {
    int d, sv;
    if (e < kEIU) { d = dst_iu[e]; sv = src_iu[e]; }
    else          { d = dst_uu[e - kEIU]; sv = src_uu[e - kEIU] | (int)0x80000000; }
    int pos = atomicAdd(&cur_u[d], 1);
    list_u[pos] = sv;
  }
}

// exclusive scan body; cnt_in may alias cursor -> NO restrict.
__device__ void scan_body(const int* cnt_in, int* starts, int* cursor, int n) {
  __shared__ int wsum[16];
  __shared__ int s_carry;
  const int tid = threadIdx.x;
  const int lane = tid & 63, wv = tid >> 6;
  if (tid == 0) s_carry = 0;
  __syncthreads();
  for (int base = 0; base < n; base += 1024) {
    int i = base + tid;
    int v = (i < n) ? cnt_in[i] : 0;
    int s = v;
    #pragma unroll
    for (int off = 1; off < 64; off <<= 1) {
      int t = __shfl_up(s, off, 64);
      if (lane >= off) s += t;
    }
    if (lane == 63) wsum[wv] = s;
    __syncthreads();
    int woff = 0, total = 0;
    #pragma unroll
    for (int w = 0; w < 16; ++w) { total += wsum[w]; woff += (w < wv) ? wsum[w] : 0; }
    int excl = s_carry + woff + s - v;
    if (i < n) { starts[i] = excl; cursor[i] = excl; }
    __syncthreads();
    if (tid == 0) s_carry += total;
    __syncthreads();
  }
  if (tid == 0) starts[n] = s_carry;
}
__global__ __launch_bounds__(1024) void scan2_kernel(
    int* cnt_i, int* starts_i, int n_i, int* cnt_u, int* starts_u, int n_u) {
  if (blockIdx.x == 0) scan_body(cnt_i, starts_i, cnt_i, n_i);
  else                 scan_body(cnt_u, starts_u, cnt_u, n_u);
}

// ---------------------------------------------------------------------------
// Wave-per-dst online-softmax aggregation, software-pipelined:
// src prefetched 2 edges ahead, kt/vt 1 edge ahead.
// 64 lanes = 8 heads x 8 lanes, float2 per lane.
// list[i] < 0 -> src in tabB (stride strideB, col offset offB); else tabA.
// ---------------------------------------------------------------------------
__global__ __launch_bounds__(256) void agg_wave_kernel(
    const int* __restrict__ starts, const int* __restrict__ list,
    const float* __restrict__ q, int qstride,
    const float* __restrict__ tabA, int strideA,
    const float* __restrict__ tabB, int strideB, int offB,
    float* __restrict__ out, int n_dst)
{
  const int dst = (int)((blockIdx.x * 256 + threadIdx.x) >> 6);
  if (dst >= n_dst) return;
  const int lane = threadIdx.x & 63;
  const int cofs = 2 * lane;            // = h*16 + 2*j
  const float2 qv = *reinterpret_cast<const float2*>(q + (size_t)dst * qstride + cofs);
  float m = -INFINITY, den = 0.f, a0 = 0.f, a1 = 0.f;
  const int i0 = starts[dst], i1 = starts[dst + 1];
  if (i0 < i1) {
    auto resolve = [&](int sv) -> const float* {
      return (sv < 0) ? tabB + (size_t)(sv & 0x7fffffff) * strideB + offB
                      : tabA + (size_t)sv * strideA;
    };
    int sv_n = list[i0];                                   // src for edge idx
    int sv_nn = (i0 + 1 < i1) ? list[i0 + 1] : 0;          // src for edge idx+1
    const float* kb = resolve(sv_n);
    float2 kk = *reinterpret_cast<const float2*>(kb + cofs);
    float2 vv = *reinterpret_cast<const float2*>(kb + 128 + cofs);
    for (int idx = i0; idx < i1; ++idx) {
      const float2 kc = kk, vc = vv;
      const int sv_next = sv_nn;
      if (idx + 2 < i1) sv_nn = list[idx + 2];
      if (idx + 1 < i1) {
        const float* kbn = resolve(sv_next);
        kk = *reinterpret_cast<const float2*>(kbn + cofs);
        vv = *reinterpret_cast<const float2*>(kbn + 128 + cofs);
      }
      float p = qv.x * kc.x + qv.y * kc.y;
      p += __shfl_xor(p, 1);
      p += __shfl_xor(p, 2);
      p += __shfl_xor(p, 4);            // score uniform within 8-lane head group
      const float mn = fmaxf(m, p);
      const float r  = __expf(m - mn);  // 0 on first edge
      const float pe = __expf(p - mn);
      den = den * r + pe;
      a0  = a0 * r + pe * vc.x;
      a1  = a1 * r + pe * vc.y;
      m = mn;
    }
  }
  const float inv = 1.f / (den + 1e-16f);
  *reinterpret_cast<float2*>(out + (size_t)dst * 128 + cofs) = make_float2(a0 * inv, a1 * inv);
}

inline int cdiv(int a, int b) { return (a + b - 1) / b; }

}  // namespace

extern "C" void kernel_launch(void* const* d_in, const int* in_sizes, int n_in,
                              void* d_out, int out_size, void* d_ws, size_t ws_size,
                              hipStream_t stream) {
  // ---- inputs (setup_inputs order) ----
  const float* x_user      = (const float*)d_in[0];
  const float* x_item      = (const float*)d_in[1];
  const int*   src_ui      = (const int*)d_in[2];
  const int*   dst_ui      = (const int*)d_in[3];
  const int*   src_iu      = (const int*)d_in[4];
  const int*   dst_iu      = (const int*)d_in[5];
  const int*   src_uu      = (const int*)d_in[6];
  const int*   dst_uu      = (const int*)d_in[7];
  const float* W_in_user   = (const float*)d_in[8];
  const float* b_in_user   = (const float*)d_in[9];
  const float* W_in_item   = (const float*)d_in[10];
  const float* b_in_item   = (const float*)d_in[11];
  const float* W_kqv_user  = (const float*)d_in[12];
  const float* b_kqv_user  = (const float*)d_in[13];
  const float* W_kqv_item  = (const float*)d_in[14];
  const float* b_kqv_item  = (const float*)d_in[15];
  const float* W_out_user  = (const float*)d_in[16];
  const float* b_out_user  = (const float*)d_in[17];
  const float* W_out_item  = (const float*)d_in[18];
  const float* b_out_item  = (const float*)d_in[19];
  const float* skip_user   = (const float*)d_in[20];
  const float* skip_item   = (const float*)d_in[21];
  const float* A_k         = (const float*)d_in[22];
  const float* A_v         = (const float*)d_in[23];
  const float* p_rel       = (const float*)d_in[24];
  const float* W_lin       = (const float*)d_in[25];
  const float* b_lin       = (const float*)d_in[26];
  float* out = (float*)d_out;
  (void)in_sizes; (void)n_in; (void)out_size; (void)ws_size;

  // ---- workspace carve-up (~124 MB, layout proven in rounds 2-4) ----
  char* base = (char*)d_ws;
  size_t off = 0;
  auto alloc = [&](size_t nbytes) -> void* {
    void* p = base + off;
    off += (nbytes + 255) & ~(size_t)255;
    return p;
  };
  float* xu    = (float*)alloc((size_t)kNU * 128 * 4);   // persistent; xi contiguous after
  float* xi    = (float*)alloc((size_t)kNI * 128 * 4);
  float* tab   = (float*)alloc((size_t)20480000 * 4);    // 81.92 MB phase-overlaid
  float* agg_u = (float*)alloc((size_t)kNU * 128 * 4);
  unsigned short* TWuU   = (unsigned short*)alloc((size_t)2 * 2 * 384 * 128 * 2);
  unsigned short* TWiU   = (unsigned short*)alloc((size_t)2 * 2 * 256 * 128 * 2);
  unsigned short* TWuI   = (unsigned short*)alloc((size_t)2 * 2 * 256 * 128 * 2);
  unsigned short* TWqi   = (unsigned short*)alloc((size_t)2 * 2 * 128 * 128 * 2);
  unsigned short* TWinU  = (unsigned short*)alloc((size_t)2 * 128 * 128 * 2);
  unsigned short* TWinI  = (unsigned short*)alloc((size_t)2 * 128 * 64 * 2);
  unsigned short* TWoutU = (unsigned short*)alloc((size_t)2 * 2 * 128 * 128 * 2);
  unsigned short* TWoutI = (unsigned short*)alloc((size_t)2 * 2 * 128 * 128 * 2);
  unsigned short* TWlin  = (unsigned short*)alloc((size_t)2 * 64 * 128 * 2);
  float* buU   = (float*)alloc((size_t)2 * 384 * 4);
  float* biU   = (float*)alloc((size_t)2 * 256 * 4);
  float* buI   = (float*)alloc((size_t)2 * 256 * 4);
  int* starts_i = (int*)alloc((size_t)(kNI + 1) * 4);
  int* cursor_i = (int*)alloc((size_t)kNI * 4);
  int* list_i   = (int*)alloc((size_t)kEUI * 4);
  int* starts_u = (int*)alloc((size_t)(kNU + 1) * 4);
  int* cursor_u = (int*)alloc((size_t)kNU * 4);
  int* list_u   = (int*)alloc((size_t)kEU * 4);

  // tab overlay (float offsets):
  // Phase U: u_all [NU x 384] (q|kt2|vt2), i_all [NI x 256] (kt1|vt1)
  // Phase I: u2 [NU x 256] (kt0|vt0), q_i [NI x 128], agg_i [NI x 128]
  float* u_all = tab + 0;
  float* i_all = tab + 7680000;
  float* u2    = tab + 0;
  float* q_i   = tab + 5120000;
  float* agg_i = tab + 11520000;

  // ---- CSR build (edge lists identical across layers -> once per call) ----
  zero2_kernel<<<cdiv(kNI, 256), 256, 0, stream>>>(cursor_i, kNI, cursor_u, kNU);
  count_all<<<cdiv(kEU, 256), 256, 0, stream>>>(dst_ui, dst_iu, dst_uu, cursor_i, cursor_u);
  scan2_kernel<<<2, 1024, 0, stream>>>(cursor_i, starts_i, kNI, cursor_u, starts_u, kNU);
  scatter_all<<<cdiv(kEU, 256), 256, 0, stream>>>(dst_ui, src_ui, dst_iu, src_iu,
                                                  dst_uu, src_uu, cursor_i, list_i,
                                                  cursor_u, list_u);

  // ---- weight prep (sliced across 368 blocks) ----
  build_weights<<<23 * kSlices, 256, 0, stream>>>(
      W_kqv_user, b_kqv_user, W_kqv_item, b_kqv_item, A_k, A_v, p_rel,
      W_in_user, W_in_item, W_out_user, W_out_item, W_lin,
      TWuU, TWiU, TWuI, TWqi, TWinU, TWinI, TWoutU, TWoutI, TWlin,
      buU, biU, buI);

  // ---- input projections (relu) ----
  mfma_gemm<0, 1><<<dim3(1, cdiv(kNU, 128)), 256, 0, stream>>>(
      x_user, TWinU, b_in_user, xu, kNU, 128, 128, nullptr, nullptr);
  mfma_gemm<0, 1><<<dim3(1, cdiv(kNI, 128)), 256, 0, stream>>>(
      x_item, TWinI, b_in_item, xi, kNI, 128, 64, nullptr, nullptr);

  for (int l = 0; l < 2; ++l) {
    // ---- phase U: q_u|kt2|vt2 from xu, kt1|vt1 from xi, aggregate to users ----
    mfma_gemm<0, 0><<<dim3(3, cdiv(kNU, 128)), 256, 0, stream>>>(
        xu, TWuU + (size_t)l * 2 * 384 * 128, buU + l * 384, u_all, kNU, 384, 128,
        nullptr, nullptr);
    mfma_gemm<0, 0><<<dim3(2, cdiv(kNI, 128)), 256, 0, stream>>>(
        xi, TWiU + (size_t)l * 2 * 256 * 128, biU + l * 256, i_all, kNI, 256, 128,
        nullptr, nullptr);
    agg_wave_kernel<<<cdiv(kNU * 64, 256), 256, 0, stream>>>(
        starts_u, list_u, u_all, 384, i_all, 256, u_all, 384, 128, agg_u, kNU);

    // ---- phase I: kt0|vt0 from xu, q_i from xi, aggregate to items ----
    mfma_gemm<0, 0><<<dim3(2, cdiv(kNU, 128)), 256, 0, stream>>>(
        xu, TWuI + (size_t)l * 2 * 256 * 128, buI + l * 256, u2, kNU, 256, 128,
        nullptr, nullptr);
    mfma_gemm<0, 0><<<dim3(1, cdiv(kNI, 128)), 256, 0, stream>>>(
        xi, TWqi + (size_t)l * 2 * 128 * 128, b_kqv_item + (size_t)l * 384 + 128,
        q_i, kNI, 128, 128, nullptr, nullptr);
    agg_wave_kernel<<<cdiv(kNI * 64, 256), 256, 0, stream>>>(
        starts_i, list_i, q_i, 128, u2, 256, u2, 256, 0, agg_i, kNI);

    // ---- out-proj: gelu -> linear -> sigmoid-gated skip -> relu (in place) ----
    mfma_gemm<1, 2><<<dim3(1, cdiv(kNU, 128)), 256, 0, stream>>>(
        agg_u, TWoutU + (size_t)l * 2 * 128 * 128, b_out_user + (size_t)l * 128,
        xu, kNU, 128, 128, xu, skip_user + l);
    mfma_gemm<1, 2><<<dim3(1, cdiv(kNI, 128)), 256, 0, stream>>>(
        agg_i, TWoutI + (size_t)l * 2 * 128 * 128, b_out_item + (size_t)l * 128,
        xi, kNI, 128, 128, xi, skip_item + l);
  }

  // ---- final shared linear over concat([xu, xi]) (contiguous in ws) ----
  mfma_gemm<0, 0><<<dim3(1, cdiv(kNU + kNI, 128)), 256, 0, stream>>>(
      xu, TWlin, b_lin, out, kNU + kNI, 64, 128, nullptr, nullptr);
}

// Round 8
// 818.982 us; speedup vs baseline: 1.5691x; 1.0696x over previous
//
#include <hip/hip_runtime.h>
#include <math.h>

namespace {

constexpr int kNU  = 20000;
constexpr int kNI  = 50000;
constexpr int kEUI = 250000;
constexpr int kEIU = 250000;
constexpr int kEUU = 125000;
constexpr int kEU  = kEIU + kEUU;   // edges with user dst (concat order: iu then uu)

typedef __attribute__((ext_vector_type(8))) short bf16x8_t;   // 8 bf16 = 4 VGPRs
typedef __attribute__((ext_vector_type(4))) float f32x4_t;    // MFMA acc

struct h2v { _Float16 x, y; };      // 4B packed half2 for table gathers

__device__ __forceinline__ float geluf(float x) {
  return 0.5f * x * (1.0f + erff(x * 0.7071067811865475f));
}

// round-to-nearest fp32 -> bf16 hi, residual -> bf16 lo
__device__ __forceinline__ void split_bf16(float x, unsigned short& hi, unsigned short& lo) {
  unsigned u = __float_as_uint(x);
  unsigned h = (u + 0x7FFFu + ((u >> 16) & 1u)) >> 16;
  hi = (unsigned short)h;
  float r = x - __uint_as_float(h << 16);
  unsigned ur = __float_as_uint(r);
  lo = (unsigned short)((ur + 0x7FFFu + ((ur >> 16) & 1u)) >> 16);
}

// ---------------------------------------------------------------------------
// MFMA GEMM (bf16x3 split precision): C = EPI( ACT_IN(A)[M,K] @ B[K,N] + bias )
// A fp32 row-major [M][K]. Bt = transposed bf16 weights [2 planes][N][K].
// OUT=0: fp32 C [M][N].
// OUT=1: mixed epilogue — cols < qcols -> fp32 C [M][qcols] (q table);
//        cols >= qcols -> fp16 Ckv [M][N-qcols] (kv table).
// Block tile 128x128, K-step 64. 4 waves, wave tile 64x64 (4x4 frags 16x16x32).
// K % 64 == 0. M, N guarded.  [core verbatim from round-4/6 pass]
// ---------------------------------------------------------------------------
template <int ACT_IN, int EPI, int OUT>
__global__ __launch_bounds__(256, 2) void mfma_gemm(
    const float* __restrict__ A, const unsigned short* __restrict__ Bt,
    const float* __restrict__ bias, float* C,
    int M, int N, int K,
    const float* x_old, const float* __restrict__ skip_scalar,
    _Float16* __restrict__ Ckv, int qcols)
{
  __shared__ unsigned short sA[2][128][72];   // [plane][m][k]
  __shared__ unsigned short sB[2][128][72];   // [plane][n][k]
  const int tid = threadIdx.x;
  const int m0 = blockIdx.y * 128, n0 = blockIdx.x * 128;
  const int lane = tid & 63, w = tid >> 6;
  const int wm = w >> 1, wn = w & 1;          // wave grid 2x2
  const int fr = lane & 15, kg = lane >> 4;
  const unsigned short* Blo = Bt + (size_t)N * K;
  const int r = tid >> 1, seg = tid & 1;      // staging: row 0..127, k-half 0..1
  f32x4_t acc[4][4] = {};

  for (int k0 = 0; k0 < K; k0 += 64) {
    // ---- stage A (fp32 -> hi/lo bf16) ----
    {
      const int arow = m0 + r;
      const bool am = arow < M;
      const float* ap = A + (size_t)arow * K + k0 + seg * 32;
      #pragma unroll
      for (int q = 0; q < 8; ++q) {
        float4 a = am ? *reinterpret_cast<const float4*>(ap + q * 4)
                      : make_float4(0.f, 0.f, 0.f, 0.f);
        if (ACT_IN == 1) { a.x = geluf(a.x); a.y = geluf(a.y); a.z = geluf(a.z); a.w = geluf(a.w); }
        ushort4 h, l;
        split_bf16(a.x, h.x, l.x); split_bf16(a.y, h.y, l.y);
        split_bf16(a.z, h.z, l.z); split_bf16(a.w, h.w, l.w);
        *reinterpret_cast<ushort4*>(&sA[0][r][seg * 32 + q * 4]) = h;
        *reinterpret_cast<ushort4*>(&sA[1][r][seg * 32 + q * 4]) = l;
      }
    }
    // ---- stage B (already bf16 hi/lo, [N][K] layout -> linear copy) ----
    {
      const int brow = n0 + r;
      const bool bm = brow < N;
      const unsigned short* bh = Bt  + (size_t)brow * K + k0 + seg * 32;
      const unsigned short* bl = Blo + (size_t)brow * K + k0 + seg * 32;
      #pragma unroll
      for (int q = 0; q < 4; ++q) {
        uint4 vh = bm ? *reinterpret_cast<const uint4*>(bh + q * 8) : make_uint4(0, 0, 0, 0);
        uint4 vl = bm ? *reinterpret_cast<const uint4*>(bl + q * 8) : make_uint4(0, 0, 0, 0);
        *reinterpret_cast<uint4*>(&sB[0][r][seg * 32 + q * 8]) = vh;
        *reinterpret_cast<uint4*>(&sB[1][r][seg * 32 + q * 8]) = vl;
      }
    }
    __syncthreads();
    #pragma unroll
    for (int ks = 0; ks < 2; ++ks) {
      const int kb = ks * 32 + kg * 8;
      bf16x8_t ah[4], al[4], bh[4], bl[4];
      #pragma unroll
      for (int fm = 0; fm < 4; ++fm) {
        const int row = wm * 64 + fm * 16 + fr;
        ah[fm] = *reinterpret_cast<const bf16x8_t*>(&sA[0][row][kb]);
        al[fm] = *reinterpret_cast<const bf16x8_t*>(&sA[1][row][kb]);
      }
      #pragma unroll
      for (int fn = 0; fn < 4; ++fn) {
        const int row = wn * 64 + fn * 16 + fr;
        bh[fn] = *reinterpret_cast<const bf16x8_t*>(&sB[0][row][kb]);
        bl[fn] = *reinterpret_cast<const bf16x8_t*>(&sB[1][row][kb]);
      }
      #pragma unroll
      for (int fm = 0; fm < 4; ++fm)
        #pragma unroll
        for (int fn = 0; fn < 4; ++fn) {
          acc[fm][fn] = __builtin_amdgcn_mfma_f32_16x16x32_bf16(ah[fm], bh[fn], acc[fm][fn], 0, 0, 0);
          acc[fm][fn] = __builtin_amdgcn_mfma_f32_16x16x32_bf16(ah[fm], bl[fn], acc[fm][fn], 0, 0, 0);
          acc[fm][fn] = __builtin_amdgcn_mfma_f32_16x16x32_bf16(al[fm], bh[fn], acc[fm][fn], 0, 0, 0);
        }
    }
    __syncthreads();
  }

  // ---- epilogue (C/D layout: col = lane&15, row = (lane>>4)*4 + reg) ----
  float g = 0.f;
  if (EPI == 2) g = 1.f / (1.f + __expf(-skip_scalar[0]));
  const int kvN = (OUT == 1) ? (N - qcols) : 0;
  #pragma unroll
  for (int fn = 0; fn < 4; ++fn) {
    const int col = n0 + wn * 64 + fn * 16 + fr;
    if (col >= N) continue;
    const float bv = bias[col];
    #pragma unroll
    for (int fm = 0; fm < 4; ++fm) {
      #pragma unroll
      for (int i = 0; i < 4; ++i) {
        const int row = m0 + wm * 64 + fm * 16 + kg * 4 + i;
        if (row >= M) continue;
        float v = acc[fm][fn][i] + bv;
        if (EPI == 1) v = fmaxf(v, 0.f);
        if (EPI == 2) {
          float xo = x_old[(size_t)row * 128 + col];   // read-then-write (may alias C)
          v = fmaxf(g * v + (1.f - g) * xo, 0.f);
        }
        if (OUT == 0) {
          C[(size_t)row * N + col] = v;
        } else {
          if (col < qcols) C[(size_t)row * qcols + col] = v;
          else             Ckv[(size_t)row * kvN + (col - qcols)] = (_Float16)v;
        }
      }
    }
  }
}

// ---------------------------------------------------------------------------
// Weight prep (sliced: grid = 23 ops x 16 slices). [verbatim round-6 pass]
// ---------------------------------------------------------------------------
constexpr int kSlices = 16;

__device__ void conv_wt(const float* __restrict__ src, int ld, int cofs,
                        int Kd, int Nd, unsigned short* __restrict__ dst, int slice) {
  const int tot = Kd * Nd;
  for (int t = slice * 256 + threadIdx.x; t < tot; t += kSlices * 256) {
    const int n = t / Kd, k = t - n * Kd;
    unsigned short h, l;
    split_bf16(src[(size_t)k * ld + cofs + n], h, l);
    dst[t] = h; dst[tot + t] = l;
  }
}

__global__ __launch_bounds__(256) void build_weights(
    const float* __restrict__ Wku, const float* __restrict__ bku,
    const float* __restrict__ Wki, const float* __restrict__ bki,
    const float* __restrict__ A_k, const float* __restrict__ A_v,
    const float* __restrict__ p_rel,
    const float* __restrict__ W_in_u, const float* __restrict__ W_in_i,
    const float* __restrict__ W_out_u, const float* __restrict__ W_out_i,
    const float* __restrict__ W_lin,
    unsigned short* __restrict__ TWuU, unsigned short* __restrict__ TWiU,
    unsigned short* __restrict__ TWuI, unsigned short* __restrict__ TWqi,
    unsigned short* __restrict__ TWinU, unsigned short* __restrict__ TWinI,
    unsigned short* __restrict__ TWoutU, unsigned short* __restrict__ TWoutI,
    unsigned short* __restrict__ TWlin,
    float* __restrict__ buU, float* __restrict__ biU, float* __restrict__ buI)
{
  const int idx = blockIdx.x >> 4;      // op id 0..22
  const int slice = blockIdx.x & 15;
  if (idx < 12) {
    const int kv = idx & 1;
    const int lr = idx >> 1;            // l*3 + r
    const int l = lr / 3, r = lr - 3 * l;
    const float* A = (kv ? A_v : A_k) + (size_t)lr * 2048;
    const float* Wsrc = (r == 1) ? (Wki + (size_t)l * 128 * 384) : (Wku + (size_t)l * 128 * 384);
    const float* bsrc = (r == 1) ? (bki + (size_t)l * 384) : (bku + (size_t)l * 384);
    const int colsrc = kv ? 256 : 0;
    unsigned short* T; float* b; int colofs, Ntot;
    if (r == 2)      { T = TWuU + (size_t)l * 2 * 384 * 128; b = buU + l * 384; colofs = 128 + kv * 128; Ntot = 384; }
    else if (r == 1) { T = TWiU + (size_t)l * 2 * 256 * 128; b = biU + l * 256; colofs = kv * 128; Ntot = 256; }
    else             { T = TWuI + (size_t)l * 2 * 256 * 128; b = buI + l * 256; colofs = kv * 128; Ntot = 256; }
    __shared__ float sA[2048];
    for (int i = threadIdx.x; i < 2048; i += 256) sA[i] = A[i];
    __syncthreads();
    const int plane = Ntot * 128;
    for (int t = slice * 256 + threadIdx.x; t < 16384; t += kSlices * 256) {
      const int c = t >> 7, hf = t & 127, h = hf >> 4, f = hf & 15;
      const float scale = kv ? 1.f : p_rel[lr * 8 + h] * 0.25f;
      const float* wrow = Wsrc + (size_t)c * 384 + colsrc + h * 16;
      float s = 0.f;
      #pragma unroll
      for (int d = 0; d < 16; ++d) s += wrow[d] * sA[h * 256 + d * 16 + f];
      unsigned short hi, lo;
      split_bf16(s * scale, hi, lo);
      T[(size_t)(colofs + hf) * 128 + c] = hi;
      T[plane + (size_t)(colofs + hf) * 128 + c] = lo;
    }
    if (slice == 0) {
      for (int t = threadIdx.x; t < 128; t += 256) {
        const int h = t >> 4, f = t & 15;
        const float scale = kv ? 1.f : p_rel[lr * 8 + h] * 0.25f;
        float s = 0.f;
        #pragma unroll
        for (int d = 0; d < 16; ++d) s += bsrc[colsrc + h * 16 + d] * sA[h * 256 + d * 16 + f];
        b[colofs + t] = s * scale;
      }
    }
    return;
  }
  if (idx < 14) {         // q_user -> TWuU rows 0..127
    const int l = idx - 12;
    const float* src = Wku + (size_t)l * 128 * 384;
    unsigned short* T = TWuU + (size_t)l * 2 * 384 * 128;
    const int plane = 384 * 128;
    for (int t = slice * 256 + threadIdx.x; t < 16384; t += kSlices * 256) {
      const int n = t >> 7, k = t & 127;
      unsigned short h, lo;
      split_bf16(src[(size_t)k * 384 + 128 + n], h, lo);
      T[(size_t)n * 128 + k] = h;
      T[plane + (size_t)n * 128 + k] = lo;
    }
    if (slice == 0)
      for (int t = threadIdx.x; t < 128; t += 256)
        buU[l * 384 + t] = bku[(size_t)l * 384 + 128 + t];
    return;
  }
  if (idx < 16) { conv_wt(Wki + (size_t)(idx - 14) * 128 * 384, 384, 128, 128, 128,
                          TWqi + (size_t)(idx - 14) * 2 * 128 * 128, slice); return; }
  if (idx == 16) { conv_wt(W_in_u, 128, 0, 128, 128, TWinU, slice); return; }
  if (idx == 17) { conv_wt(W_in_i, 128, 0, 64, 128, TWinI, slice); return; }
  if (idx < 20) { conv_wt(W_out_u + (size_t)(idx - 18) * 16384, 128, 0, 128, 128,
                          TWoutU + (size_t)(idx - 18) * 2 * 16384, slice); return; }
  if (idx < 22) { conv_wt(W_out_i + (size_t)(idx - 20) * 16384, 128, 0, 128, 128,
                          TWoutI + (size_t)(idx - 20) * 2 * 16384, slice); return; }
  conv_wt(W_lin, 64, 0, 128, 64, TWlin, slice);
}

// ---------------------------------------------------------------------------
// CSR build. list stores SRC id; bit31 -> tabB in user agg. [verbatim round-6]
// ---------------------------------------------------------------------------
__global__ void zero2_kernel(int* a, int na, int* b, int nb) {
  int i = blockIdx.x * 256 + threadIdx.x;
  if (i < na) a[i] = 0;
  if (i < nb) b[i] = 0;
}
__global__ void count_all(const int* __restrict__ dst_ui, const int* __restrict__ dst_iu,
                          const int* __restrict__ dst_uu,
                          int* __restrict__ cnt_i, int* __restrict__ cnt_u) {
  int e = blockIdx.x * 256 + threadIdx.x;
  if (e < kEUI) atomicAdd(&cnt_i[dst_ui[e]], 1);
  if (e < kEU) {
    int d = (e < kEIU) ? dst_iu[e] : dst_uu[e - kEIU];
    atomicAdd(&cnt_u[d], 1);
  }
}
__global__ void scatter_all(const int* __restrict__ dst_ui, const int* __restrict__ src_ui,
                            const int* __restrict__ dst_iu, const int* __restrict__ src_iu,
                            const int* __restrict__ dst_uu, const int* __restrict__ src_uu,
                            int* __restrict__ cur_i, int* __restrict__ list_i,
                            int* __restrict__ cur_u, int* __restrict__ list_u) {
  int e = blockIdx.x * 256 + threadIdx.x;
  if (e < kEUI) { int pos = atomicAdd(&cur_i[dst_ui[e]], 1); list_i[pos] = src_ui[e]; }
  if (e < kEU) {
    int d, sv;
    if (e < kEIU) { d = dst_iu[e]; sv = src_iu[e]; }
    else          { d = dst_uu[e - kEIU]; sv = src_uu[e - kEIU] | (int)0x80000000; }
    int pos = atomicAdd(&cur_u[d], 1);
    list_u[pos] = sv;
  }
}

// exclusive scan body; cnt_in may alias cursor -> NO restrict.
__device__ void scan_body(const int* cnt_in, int* starts, int* cursor, int n) {
  __shared__ int wsum[16];
  __shared__ int s_carry;
  const int tid = threadIdx.x;
  const int lane = tid & 63, wv = tid >> 6;
  if (tid == 0) s_carry = 0;
  __syncthreads();
  for (int base = 0; base < n; base += 1024) {
    int i = base + tid;
    int v = (i < n) ? cnt_in[i] : 0;
    int s = v;
    #pragma unroll
    for (int off = 1; off < 64; off <<= 1) {
      int t = __shfl_up(s, off, 64);
      if (lane >= off) s += t;
    }
    if (lane == 63) wsum[wv] = s;
    __syncthreads();
    int woff = 0, total = 0;
    #pragma unroll
    for (int w = 0; w < 16; ++w) { total += wsum[w]; woff += (w < wv) ? wsum[w] : 0; }
    int excl = s_carry + woff + s - v;
    if (i < n) { starts[i] = excl; cursor[i] = excl; }
    __syncthreads();
    if (tid == 0) s_carry += total;
    __syncthreads();
  }
  if (tid == 0) starts[n] = s_carry;
}
__global__ __launch_bounds__(1024) void scan2_kernel(
    int* cnt_i, int* starts_i, int n_i, int* cnt_u, int* starts_u, int n_u) {
  if (blockIdx.x == 0) scan_body(cnt_i, starts_i, cnt_i, n_i);
  else                 scan_body(cnt_u, starts_u, cnt_u, n_u);
}

// ---------------------------------------------------------------------------
// Wave-per-dst online-softmax aggregation over fp16 kv tables.
// 64 lanes = 8 heads x 8 lanes, half2 (4B) per lane for k and for v.
// kv table row: 256 halves = [kt 0..127 | vt 128..255], stride 256.
// q fp32 [n][128]. list[i] < 0 -> src row in tabB; else tabA.
// Simple round-4 loop shape (2-deep prefetch measurably hurt in round 6).
// ---------------------------------------------------------------------------
__global__ __launch_bounds__(256) void agg_wave_kernel(
    const int* __restrict__ starts, const int* __restrict__ list,
    const float* __restrict__ q,
    const _Float16* __restrict__ tabA, const _Float16* __restrict__ tabB,
    float* __restrict__ out, int n_dst)
{
  const int dst = (int)((blockIdx.x * 256 + threadIdx.x) >> 6);
  if (dst >= n_dst) return;
  const int lane = threadIdx.x & 63;
  const int cofs = 2 * lane;            // = h*16 + 2*j
  const float2 qv = *reinterpret_cast<const float2*>(q + (size_t)dst * 128 + cofs);
  float m = -INFINITY, den = 0.f, a0 = 0.f, a1 = 0.f;
  const int i1 = starts[dst + 1];
  int idx = starts[dst];
  int sv_next = (idx < i1) ? list[idx] : 0;
  for (; idx < i1; ++idx) {
    const int sv = sv_next;
    if (idx + 1 < i1) sv_next = list[idx + 1];
    const _Float16* kb = (sv < 0) ? tabB + (size_t)(sv & 0x7fffffff) * 256
                                  : tabA + (size_t)sv * 256;
    const h2v kk = *reinterpret_cast<const h2v*>(kb + cofs);
    const h2v vv = *reinterpret_cast<const h2v*>(kb + 128 + cofs);
    float p = qv.x * (float)kk.x + qv.y * (float)kk.y;
    p += __shfl_xor(p, 1);
    p += __shfl_xor(p, 2);
    p += __shfl_xor(p, 4);              // score uniform within 8-lane head group
    const float mn = fmaxf(m, p);
    const float r  = __expf(m - mn);    // 0 on first edge
    const float pe = __expf(p - mn);
    den = den * r + pe;
    a0  = a0 * r + pe * (float)vv.x;
    a1  = a1 * r + pe * (float)vv.y;
    m = mn;
  }
  const float inv = 1.f / (den + 1e-16f);
  *reinterpret_cast<float2*>(out + (size_t)dst * 128 + cofs) = make_float2(a0 * inv, a1 * inv);
}

inline int cdiv(int a, int b) { return (a + b - 1) / b; }

}  // namespace

extern "C" void kernel_launch(void* const* d_in, const int* in_sizes, int n_in,
                              void* d_out, int out_size, void* d_ws, size_t ws_size,
                              hipStream_t stream) {
  // ---- inputs (setup_inputs order) ----
  const float* x_user      = (const float*)d_in[0];
  const float* x_item      = (const float*)d_in[1];
  const int*   src_ui      = (const int*)d_in[2];
  const int*   dst_ui      = (const int*)d_in[3];
  const int*   src_iu      = (const int*)d_in[4];
  const int*   dst_iu      = (const int*)d_in[5];
  const int*   src_uu      = (const int*)d_in[6];
  const int*   dst_uu      = (const int*)d_in[7];
  const float* W_in_user   = (const float*)d_in[8];
  const float* b_in_user   = (const float*)d_in[9];
  const float* W_in_item   = (const float*)d_in[10];
  const float* b_in_item   = (const float*)d_in[11];
  const float* W_kqv_user  = (const float*)d_in[12];
  const float* b_kqv_user  = (const float*)d_in[13];
  const float* W_kqv_item  = (const float*)d_in[14];
  const float* b_kqv_item  = (const float*)d_in[15];
  const float* W_out_user  = (const float*)d_in[16];
  const float* b_out_user  = (const float*)d_in[17];
  const float* W_out_item  = (const float*)d_in[18];
  const float* b_out_item  = (const float*)d_in[19];
  const float* skip_user   = (const float*)d_in[20];
  const float* skip_item   = (const float*)d_in[21];
  const float* A_k         = (const float*)d_in[22];
  const float* A_v         = (const float*)d_in[23];
  const float* p_rel       = (const float*)d_in[24];
  const float* W_lin       = (const float*)d_in[25];
  const float* b_lin       = (const float*)d_in[26];
  float* out = (float*)d_out;
  (void)in_sizes; (void)n_in; (void)out_size; (void)ws_size;

  // ---- workspace carve-up (same proven budget; tab shrinks) ----
  char* base = (char*)d_ws;
  size_t off = 0;
  auto alloc = [&](size_t nbytes) -> void* {
    void* p = base + off;
    off += (nbytes + 255) & ~(size_t)255;
    return p;
  };
  float* xu    = (float*)alloc((size_t)kNU * 128 * 4);   // persistent; xi contiguous after
  float* xi    = (float*)alloc((size_t)kNI * 128 * 4);
  float* tab   = (float*)alloc((size_t)15360000 * 4);    // 61.44 MB phase-overlaid
  float* agg_u = (float*)alloc((size_t)kNU * 128 * 4);
  unsigned short* TWuU   = (unsigned short*)alloc((size_t)2 * 2 * 384 * 128 * 2);
  unsigned short* TWiU   = (unsigned short*)alloc((size_t)2 * 2 * 256 * 128 * 2);
  unsigned short* TWuI   = (unsigned short*)alloc((size_t)2 * 2 * 256 * 128 * 2);
  unsigned short* TWqi   = (unsigned short*)alloc((size_t)2 * 2 * 128 * 128 * 2);
  unsigned short* TWinU  = (unsigned short*)alloc((size_t)2 * 128 * 128 * 2);
  unsigned short* TWinI  = (unsigned short*)alloc((size_t)2 * 128 * 64 * 2);
  unsigned short* TWoutU = (unsigned short*)alloc((size_t)2 * 2 * 128 * 128 * 2);
  unsigned short* TWoutI = (unsigned short*)alloc((size_t)2 * 2 * 128 * 128 * 2);
  unsigned short* TWlin  = (unsigned short*)alloc((size_t)2 * 64 * 128 * 2);
  float* buU   = (float*)alloc((size_t)2 * 384 * 4);
  float* biU   = (float*)alloc((size_t)2 * 256 * 4);
  float* buI   = (float*)alloc((size_t)2 * 256 * 4);
  int* starts_i = (int*)alloc((size_t)(kNI + 1) * 4);
  int* cursor_i = (int*)alloc((size_t)kNI * 4);
  int* list_i   = (int*)alloc((size_t)kEUI * 4);
  int* starts_u = (int*)alloc((size_t)(kNU + 1) * 4);
  int* cursor_u = (int*)alloc((size_t)kNU * 4);
  int* list_u   = (int*)alloc((size_t)kEU * 4);

  // tab overlay (float-slot offsets):
  // Phase U: q_u fp32 [NU][128] @0 (2.56M) | u_kv2 half [NU][256] @2.56M (2.56M)
  //          | i_kv half [NI][256] @5.12M (6.4M)  -> ends 11.52M
  // Phase I: u_kv0 half [NU][256] @0 (2.56M) | q_i fp32 [NI][128] @2.56M (6.4M)
  //          | agg_i fp32 [NI][128] @8.96M (6.4M) -> ends 15.36M
  float*    q_u   = tab + 0;
  _Float16* u_kv2 = (_Float16*)(tab + 2560000);
  _Float16* i_kv  = (_Float16*)(tab + 5120000);
  _Float16* u_kv0 = (_Float16*)(tab + 0);
  float*    q_i   = tab + 2560000;
  float*    agg_i = tab + 8960000;

  // ---- CSR build (edge lists identical across layers -> once per call) ----
  zero2_kernel<<<cdiv(kNI, 256), 256, 0, stream>>>(cursor_i, kNI, cursor_u, kNU);
  count_all<<<cdiv(kEU, 256), 256, 0, stream>>>(dst_ui, dst_iu, dst_uu, cursor_i, cursor_u);
  scan2_kernel<<<2, 1024, 0, stream>>>(cursor_i, starts_i, kNI, cursor_u, starts_u, kNU);
  scatter_all<<<cdiv(kEU, 256), 256, 0, stream>>>(dst_ui, src_ui, dst_iu, src_iu,
                                                  dst_uu, src_uu, cursor_i, list_i,
                                                  cursor_u, list_u);

  // ---- weight prep (sliced across 368 blocks) ----
  build_weights<<<23 * kSlices, 256, 0, stream>>>(
      W_kqv_user, b_kqv_user, W_kqv_item, b_kqv_item, A_k, A_v, p_rel,
      W_in_user, W_in_item, W_out_user, W_out_item, W_lin,
      TWuU, TWiU, TWuI, TWqi, TWinU, TWinI, TWoutU, TWoutI, TWlin,
      buU, biU, buI);

  // ---- input projections (relu) ----
  mfma_gemm<0, 1, 0><<<dim3(1, cdiv(kNU, 128)), 256, 0, stream>>>(
      x_user, TWinU, b_in_user, xu, kNU, 128, 128, nullptr, nullptr, nullptr, 0);
  mfma_gemm<0, 1, 0><<<dim3(1, cdiv(kNI, 128)), 256, 0, stream>>>(
      x_item, TWinI, b_in_item, xi, kNI, 128, 64, nullptr, nullptr, nullptr, 0);

  for (int l = 0; l < 2; ++l) {
    // ---- phase U: [q_u fp32 | kt2|vt2 fp16] from xu; [kt1|vt1 fp16] from xi ----
    mfma_gemm<0, 0, 1><<<dim3(3, cdiv(kNU, 128)), 256, 0, stream>>>(
        xu, TWuU + (size_t)l * 2 * 384 * 128, buU + l * 384, q_u, kNU, 384, 128,
        nullptr, nullptr, u_kv2, 128);
    mfma_gemm<0, 0, 1><<<dim3(2, cdiv(kNI, 128)), 256, 0, stream>>>(
        xi, TWiU + (size_t)l * 2 * 256 * 128, biU + l * 256, nullptr, kNI, 256, 128,
        nullptr, nullptr, i_kv, 0);
    agg_wave_kernel<<<cdiv(kNU * 64, 256), 256, 0, stream>>>(
        starts_u, list_u, q_u, i_kv, u_kv2, agg_u, kNU);

    // ---- phase I: [kt0|vt0 fp16] from xu; q_i fp32 from xi ----
    mfma_gemm<0, 0, 1><<<dim3(2, cdiv(kNU, 128)), 256, 0, stream>>>(
        xu, TWuI + (size_t)l * 2 * 256 * 128, buI + l * 256, nullptr, kNU, 256, 128,
        nullptr, nullptr, u_kv0, 0);
    mfma_gemm<0, 0, 0><<<dim3(1, cdiv(kNI, 128)), 256, 0, stream>>>(
        xi, TWqi + (size_t)l * 2 * 128 * 128, b_kqv_item + (size_t)l * 384 + 128,
        q_i, kNI, 128, 128, nullptr, nullptr, nullptr, 0);
    agg_wave_kernel<<<cdiv(kNI * 64, 256), 256, 0, stream>>>(
        starts_i, list_i, q_i, u_kv0, u_kv0, agg_i, kNI);

    // ---- out-proj: gelu -> linear -> sigmoid-gated skip -> relu (in place) ----
    mfma_gemm<1, 2, 0><<<dim3(1, cdiv(kNU, 128)), 256, 0, stream>>>(
        agg_u, TWoutU + (size_t)l * 2 * 128 * 128, b_out_user + (size_t)l * 128,
        xu, kNU, 128, 128, xu, skip_user + l, nullptr, 0);
    mfma_gemm<1, 2, 0><<<dim3(1, cdiv(kNI, 128)), 256, 0, stream>>>(
        agg_i, TWoutI + (size_t)l * 2 * 128 * 128, b_out_item + (size_t)l * 128,
        xi, kNI, 128, 128, xi, skip_item + l, nullptr, 0);
  }

  // ---- final shared linear over concat([xu, xi]) (contiguous in ws) ----
  mfma_gemm<0, 0, 0><<<dim3(1, cdiv(kNU + kNI, 128)), 256, 0, stream>>>(
      xu, TWlin, b_lin, out, kNU + kNI, 64, 128, nullptr, nullptr, nullptr, 0);
}

// Round 9
// 755.732 us; speedup vs baseline: 1.7005x; 1.0837x over previous
//
#include <hip/hip_runtime.h>
#include <math.h>

namespace {

constexpr int kNU  = 20000;
constexpr int kNI  = 50000;
constexpr int kEUI = 250000;
constexpr int kEIU = 250000;
constexpr int kEUU = 125000;
constexpr int kEU  = kEIU + kEUU;   // edges with user dst (concat order: iu then uu)

typedef __attribute__((ext_vector_type(8))) short bf16x8_t;   // 8 bf16 = 4 VGPRs
typedef __attribute__((ext_vector_type(4))) float f32x4_t;    // MFMA acc

struct h2v { _Float16 x, y; };      // 4B packed half2 for table gathers

__device__ __forceinline__ float geluf(float x) {
  return 0.5f * x * (1.0f + erff(x * 0.7071067811865475f));
}

// round-to-nearest fp32 -> bf16 hi, residual -> bf16 lo
__device__ __forceinline__ void split_bf16(float x, unsigned short& hi, unsigned short& lo) {
  unsigned u = __float_as_uint(x);
  unsigned h = (u + 0x7FFFu + ((u >> 16) & 1u)) >> 16;
  hi = (unsigned short)h;
  float r = x - __uint_as_float(h << 16);
  unsigned ur = __float_as_uint(r);
  lo = (unsigned short)((ur + 0x7FFFu + ((ur >> 16) & 1u)) >> 16);
}

// ---------------------------------------------------------------------------
// MFMA GEMM (bf16x3 split precision): C = EPI( ACT_IN(A)[M,K] @ B[K,N] + bias )
// A fp32 row-major [M][K]. Bt = transposed bf16 weights [2 planes][N][K].
// OUT=0: fp32 C [M][N].
// OUT=1: mixed epilogue — cols < qcols -> fp32 C [M][qcols] (q table);
//        cols >= qcols -> fp16 Ckv [M][N-qcols] (kv table).
// Block tile 128x128, K-step 32 (4 blocks/CU: LDS 2x18KB, launch_bounds 256,4 —
// round-8 K-step 64 / 72KB / 2 blocks/CU was occupancy-bound at 15%).
// 4 waves, wave tile 64x64 (4x4 frags 16x16x32). K % 32 == 0. M, N guarded.
// ---------------------------------------------------------------------------
template <int ACT_IN, int EPI, int OUT>
__global__ __launch_bounds__(256, 4) void mfma_gemm(
    const float* __restrict__ A, const unsigned short* __restrict__ Bt,
    const float* __restrict__ bias, float* C,
    int M, int N, int K,
    const float* x_old, const float* __restrict__ skip_scalar,
    _Float16* __restrict__ Ckv, int qcols)
{
  __shared__ unsigned short sA[2][128][36];   // [plane][m][k], +4 pad (72B stride)
  __shared__ unsigned short sB[2][128][36];   // [plane][n][k]
  const int tid = threadIdx.x;
  const int m0 = blockIdx.y * 128, n0 = blockIdx.x * 128;
  const int lane = tid & 63, w = tid >> 6;
  const int wm = w >> 1, wn = w & 1;          // wave grid 2x2
  const int fr = lane & 15, kg = lane >> 4;
  const unsigned short* Blo = Bt + (size_t)N * K;
  const int r = tid >> 1, seg = tid & 1;      // staging: row 0..127, k-half (16 each)
  f32x4_t acc[4][4] = {};

  for (int k0 = 0; k0 < K; k0 += 32) {
    // ---- stage A (fp32 -> hi/lo bf16): 4 x float4 = 16 floats/thread ----
    {
      const int arow = m0 + r;
      const bool am = arow < M;
      const float* ap = A + (size_t)arow * K + k0 + seg * 16;
      #pragma unroll
      for (int q = 0; q < 4; ++q) {
        float4 a = am ? *reinterpret_cast<const float4*>(ap + q * 4)
                      : make_float4(0.f, 0.f, 0.f, 0.f);
        if (ACT_IN == 1) { a.x = geluf(a.x); a.y = geluf(a.y); a.z = geluf(a.z); a.w = geluf(a.w); }
        ushort4 h, l;
        split_bf16(a.x, h.x, l.x); split_bf16(a.y, h.y, l.y);
        split_bf16(a.z, h.z, l.z); split_bf16(a.w, h.w, l.w);
        *reinterpret_cast<ushort4*>(&sA[0][r][seg * 16 + q * 4]) = h;
        *reinterpret_cast<ushort4*>(&sA[1][r][seg * 16 + q * 4]) = l;
      }
    }
    // ---- stage B (bf16 hi/lo, [N][K] layout -> linear copy): 2 x uint4/plane ----
    {
      const int brow = n0 + r;
      const bool bm = brow < N;
      const unsigned short* bh = Bt  + (size_t)brow * K + k0 + seg * 16;
      const unsigned short* bl = Blo + (size_t)brow * K + k0 + seg * 16;
      #pragma unroll
      for (int q = 0; q < 2; ++q) {
        uint4 vh = bm ? *reinterpret_cast<const uint4*>(bh + q * 8) : make_uint4(0, 0, 0, 0);
        uint4 vl = bm ? *reinterpret_cast<const uint4*>(bl + q * 8) : make_uint4(0, 0, 0, 0);
        *reinterpret_cast<uint4*>(&sB[0][r][seg * 16 + q * 8]) = vh;
        *reinterpret_cast<uint4*>(&sB[1][r][seg * 16 + q * 8]) = vl;
      }
    }
    __syncthreads();
    {
      const int kb = kg * 8;                  // k-group covers 32 k
      bf16x8_t ah[4], al[4], bh[4], bl[4];
      #pragma unroll
      for (int fm = 0; fm < 4; ++fm) {
        const int row = wm * 64 + fm * 16 + fr;
        ah[fm] = *reinterpret_cast<const bf16x8_t*>(&sA[0][row][kb]);
        al[fm] = *reinterpret_cast<const bf16x8_t*>(&sA[1][row][kb]);
      }
      #pragma unroll
      for (int fn = 0; fn < 4; ++fn) {
        const int row = wn * 64 + fn * 16 + fr;
        bh[fn] = *reinterpret_cast<const bf16x8_t*>(&sB[0][row][kb]);
        bl[fn] = *reinterpret_cast<const bf16x8_t*>(&sB[1][row][kb]);
      }
      #pragma unroll
      for (int fm = 0; fm < 4; ++fm)
        #pragma unroll
        for (int fn = 0; fn < 4; ++fn) {
          acc[fm][fn] = __builtin_amdgcn_mfma_f32_16x16x32_bf16(ah[fm], bh[fn], acc[fm][fn], 0, 0, 0);
          acc[fm][fn] = __builtin_amdgcn_mfma_f32_16x16x32_bf16(ah[fm], bl[fn], acc[fm][fn], 0, 0, 0);
          acc[fm][fn] = __builtin_amdgcn_mfma_f32_16x16x32_bf16(al[fm], bh[fn], acc[fm][fn], 0, 0, 0);
        }
    }
    __syncthreads();
  }

  // ---- epilogue (C/D layout: col = lane&15, row = (lane>>4)*4 + reg) ----
  float g = 0.f;
  if (EPI == 2) g = 1.f / (1.f + __expf(-skip_scalar[0]));
  const int kvN = (OUT == 1) ? (N - qcols) : 0;
  #pragma unroll
  for (int fn = 0; fn < 4; ++fn) {
    const int col = n0 + wn * 64 + fn * 16 + fr;
    if (col >= N) continue;
    const float bv = bias[col];
    #pragma unroll
    for (int fm = 0; fm < 4; ++fm) {
      #pragma unroll
      for (int i = 0; i < 4; ++i) {
        const int row = m0 + wm * 64 + fm * 16 + kg * 4 + i;
        if (row >= M) continue;
        float v = acc[fm][fn][i] + bv;
        if (EPI == 1) v = fmaxf(v, 0.f);
        if (EPI == 2) {
          float xo = x_old[(size_t)row * 128 + col];   // read-then-write (may alias C)
          v = fmaxf(g * v + (1.f - g) * xo, 0.f);
        }
        if (OUT == 0) {
          C[(size_t)row * N + col] = v;
        } else {
          if (col < qcols) C[(size_t)row * qcols + col] = v;
          else             Ckv[(size_t)row * kvN + (col - qcols)] = (_Float16)v;
        }
      }
    }
  }
}

// ---------------------------------------------------------------------------
// Weight prep (sliced: grid = 23 ops x 16 slices). [verbatim round-6/8 pass]
// ---------------------------------------------------------------------------
constexpr int kSlices = 16;

__device__ void conv_wt(const float* __restrict__ src, int ld, int cofs,
                        int Kd, int Nd, unsigned short* __restrict__ dst, int slice) {
  const int tot = Kd * Nd;
  for (int t = slice * 256 + threadIdx.x; t < tot; t += kSlices * 256) {
    const int n = t / Kd, k = t - n * Kd;
    unsigned short h, l;
    split_bf16(src[(size_t)k * ld + cofs + n], h, l);
    dst[t] = h; dst[tot + t] = l;
  }
}

__global__ __launch_bounds__(256) void build_weights(
    const float* __restrict__ Wku, const float* __restrict__ bku,
    const float* __restrict__ Wki, const float* __restrict__ bki,
    const float* __restrict__ A_k, const float* __restrict__ A_v,
    const float* __restrict__ p_rel,
    const float* __restrict__ W_in_u, const float* __restrict__ W_in_i,
    const float* __restrict__ W_out_u, const float* __restrict__ W_out_i,
    const float* __restrict__ W_lin,
    unsigned short* __restrict__ TWuU, unsigned short* __restrict__ TWiU,
    unsigned short* __restrict__ TWuI, unsigned short* __restrict__ TWqi,
    unsigned short* __restrict__ TWinU, unsigned short* __restrict__ TWinI,
    unsigned short* __restrict__ TWoutU, unsigned short* __restrict__ TWoutI,
    unsigned short* __restrict__ TWlin,
    float* __restrict__ buU, float* __restrict__ biU, float* __restrict__ buI)
{
  const int idx = blockIdx.x >> 4;      // op id 0..22
  const int slice = blockIdx.x & 15;
  if (idx < 12) {
    const int kv = idx & 1;
    const int lr = idx >> 1;            // l*3 + r
    const int l = lr / 3, r = lr - 3 * l;
    const float* A = (kv ? A_v : A_k) + (size_t)lr * 2048;
    const float* Wsrc = (r == 1) ? (Wki + (size_t)l * 128 * 384) : (Wku + (size_t)l * 128 * 384);
    const float* bsrc = (r == 1) ? (bki + (size_t)l * 384) : (bku + (size_t)l * 384);
    const int colsrc = kv ? 256 : 0;
    unsigned short* T; float* b; int colofs, Ntot;
    if (r == 2)      { T = TWuU + (size_t)l * 2 * 384 * 128; b = buU + l * 384; colofs = 128 + kv * 128; Ntot = 384; }
    else if (r == 1) { T = TWiU + (size_t)l * 2 * 256 * 128; b = biU + l * 256; colofs = kv * 128; Ntot = 256; }
    else             { T = TWuI + (size_t)l * 2 * 256 * 128; b = buI + l * 256; colofs = kv * 128; Ntot = 256; }
    __shared__ float sA[2048];
    for (int i = threadIdx.x; i < 2048; i += 256) sA[i] = A[i];
    __syncthreads();
    const int plane = Ntot * 128;
    for (int t = slice * 256 + threadIdx.x; t < 16384; t += kSlices * 256) {
      const int c = t >> 7, hf = t & 127, h = hf >> 4, f = hf & 15;
      const float scale = kv ? 1.f : p_rel[lr * 8 + h] * 0.25f;
      const float* wrow = Wsrc + (size_t)c * 384 + colsrc + h * 16;
      float s = 0.f;
      #pragma unroll
      for (int d = 0; d < 16; ++d) s += wrow[d] * sA[h * 256 + d * 16 + f];
      unsigned short hi, lo;
      split_bf16(s * scale, hi, lo);
      T[(size_t)(colofs + hf) * 128 + c] = hi;
      T[plane + (size_t)(colofs + hf) * 128 + c] = lo;
    }
    if (slice == 0) {
      for (int t = threadIdx.x; t < 128; t += 256) {
        const int h = t >> 4, f = t & 15;
        const float scale = kv ? 1.f : p_rel[lr * 8 + h] * 0.25f;
        float s = 0.f;
        #pragma unroll
        for (int d = 0; d < 16; ++d) s += bsrc[colsrc + h * 16 + d] * sA[h * 256 + d * 16 + f];
        b[colofs + t] = s * scale;
      }
    }
    return;
  }
  if (idx < 14) {         // q_user -> TWuU rows 0..127
    const int l = idx - 12;
    const float* src = Wku + (size_t)l * 128 * 384;
    unsigned short* T = TWuU + (size_t)l * 2 * 384 * 128;
    const int plane = 384 * 128;
    for (int t = slice * 256 + threadIdx.x; t < 16384; t += kSlices * 256) {
      const int n = t >> 7, k = t & 127;
      unsigned short h, lo;
      split_bf16(src[(size_t)k * 384 + 128 + n], h, lo);
      T[(size_t)n * 128 + k] = h;
      T[plane + (size_t)n * 128 + k] = lo;
    }
    if (slice == 0)
      for (int t = threadIdx.x; t < 128; t += 256)
        buU[l * 384 + t] = bku[(size_t)l * 384 + 128 + t];
    return;
  }
  if (idx < 16) { conv_wt(Wki + (size_t)(idx - 14) * 128 * 384, 384, 128, 128, 128,
                          TWqi + (size_t)(idx - 14) * 2 * 128 * 128, slice); return; }
  if (idx == 16) { conv_wt(W_in_u, 128, 0, 128, 128, TWinU, slice); return; }
  if (idx == 17) { conv_wt(W_in_i, 128, 0, 64, 128, TWinI, slice); return; }
  if (idx < 20) { conv_wt(W_out_u + (size_t)(idx - 18) * 16384, 128, 0, 128, 128,
                          TWoutU + (size_t)(idx - 18) * 2 * 16384, slice); return; }
  if (idx < 22) { conv_wt(W_out_i + (size_t)(idx - 20) * 16384, 128, 0, 128, 128,
                          TWoutI + (size_t)(idx - 20) * 2 * 16384, slice); return; }
  conv_wt(W_lin, 64, 0, 128, 64, TWlin, slice);
}

// ---------------------------------------------------------------------------
// CSR build. list stores SRC id; bit31 -> tabB in user agg. [verbatim round-6/8]
// ---------------------------------------------------------------------------
__global__ void zero2_kernel(int* a, int na, int* b, int nb) {
  int i = blockIdx.x * 256 + threadIdx.x;
  if (i < na) a[i] = 0;
  if (i < nb) b[i] = 0;
}
__global__ void count_all(const int* __restrict__ dst_ui, const int* __restrict__ dst_iu,
                          const int* __restrict__ dst_uu,
                          int* __restrict__ cnt_i, int* __restrict__ cnt_u) {
  int e = blockIdx.x * 256 + threadIdx.x;
  if (e < kEUI) atomicAdd(&cnt_i[dst_ui[e]], 1);
  if (e < kEU) {
    int d = (e < kEIU) ? dst_iu[e] : dst_uu[e - kEIU];
    atomicAdd(&cnt_u[d], 1);
  }
}
__global__ void scatter_all(const int* __restrict__ dst_ui, const int* __restrict__ src_ui,
                            const int* __restrict__ dst_iu, const int* __restrict__ src_iu,
                            const int* __restrict__ dst_uu, const int* __restrict__ src_uu,
                            int* __restrict__ cur_i, int* __restrict__ list_i,
                            int* __restrict__ cur_u, int* __restrict__ list_u) {
  int e = blockIdx.x * 256 + threadIdx.x;
  if (e < kEUI) { int pos = atomicAdd(&cur_i[dst_ui[e]], 1); list_i[pos] = src_ui[e]; }
  if (e < kEU) {
    int d, sv;
    if (e < kEIU) { d = dst_iu[e]; sv = src_iu[e]; }
    else          { d = dst_uu[e - kEIU]; sv = src_uu[e - kEIU] | (int)0x80000000; }
    int pos = atomicAdd(&cur_u[d], 1);
    list_u[pos] = sv;
  }
}

// exclusive scan body; cnt_in may alias cursor -> NO restrict.
__device__ void scan_body(const int* cnt_in, int* starts, int* cursor, int n) {
  __shared__ int wsum[16];
  __shared__ int s_carry;
  const int tid = threadIdx.x;
  const int lane = tid & 63, wv = tid >> 6;
  if (tid == 0) s_carry = 0;
  __syncthreads();
  for (int base = 0; base < n; base += 1024) {
    int i = base + tid;
    int v = (i < n) ? cnt_in[i] : 0;
    int s = v;
    #pragma unroll
    for (int off = 1; off < 64; off <<= 1) {
      int t = __shfl_up(s, off, 64);
      if (lane >= off) s += t;
    }
    if (lane == 63) wsum[wv] = s;
    __syncthreads();
    int woff = 0, total = 0;
    #pragma unroll
    for (int w = 0; w < 16; ++w) { total += wsum[w]; woff += (w < wv) ? wsum[w] : 0; }
    int excl = s_carry + woff + s - v;
    if (i < n) { starts[i] = excl; cursor[i] = excl; }
    __syncthreads();
    if (tid == 0) s_carry += total;
    __syncthreads();
  }
  if (tid == 0) starts[n] = s_carry;
}
__global__ __launch_bounds__(1024) void scan2_kernel(
    int* cnt_i, int* starts_i, int n_i, int* cnt_u, int* starts_u, int n_u) {
  if (blockIdx.x == 0) scan_body(cnt_i, starts_i, cnt_i, n_i);
  else                 scan_body(cnt_u, starts_u, cnt_u, n_u);
}

// ---------------------------------------------------------------------------
// Wave-per-dst online-softmax aggregation over fp16 kv tables. [verbatim r8]
// 64 lanes = 8 heads x 8 lanes, half2 (4B) per lane for k and for v.
// kv table row: 256 halves = [kt 0..127 | vt 128..255], stride 256.
// q fp32 [n][128]. list[i] < 0 -> src row in tabB; else tabA.
// ---------------------------------------------------------------------------
__global__ __launch_bounds__(256) void agg_wave_kernel(
    const int* __restrict__ starts, const int* __restrict__ list,
    const float* __restrict__ q,
    const _Float16* __restrict__ tabA, const _Float16* __restrict__ tabB,
    float* __restrict__ out, int n_dst)
{
  const int dst = (int)((blockIdx.x * 256 + threadIdx.x) >> 6);
  if (dst >= n_dst) return;
  const int lane = threadIdx.x & 63;
  const int cofs = 2 * lane;            // = h*16 + 2*j
  const float2 qv = *reinterpret_cast<const float2*>(q + (size_t)dst * 128 + cofs);
  float m = -INFINITY, den = 0.f, a0 = 0.f, a1 = 0.f;
  const int i1 = starts[dst + 1];
  int idx = starts[dst];
  int sv_next = (idx < i1) ? list[idx] : 0;
  for (; idx < i1; ++idx) {
    const int sv = sv_next;
    if (idx + 1 < i1) sv_next = list[idx + 1];
    const _Float16* kb = (sv < 0) ? tabB + (size_t)(sv & 0x7fffffff) * 256
                                  : tabA + (size_t)sv * 256;
    const h2v kk = *reinterpret_cast<const h2v*>(kb + cofs);
    const h2v vv = *reinterpret_cast<const h2v*>(kb + 128 + cofs);
    float p = qv.x * (float)kk.x + qv.y * (float)kk.y;
    p += __shfl_xor(p, 1);
    p += __shfl_xor(p, 2);
    p += __shfl_xor(p, 4);              // score uniform within 8-lane head group
    const float mn = fmaxf(m, p);
    const float r  = __expf(m - mn);    // 0 on first edge
    const float pe = __expf(p - mn);
    den = den * r + pe;
    a0  = a0 * r + pe * (float)vv.x;
    a1  = a1 * r + pe * (float)vv.y;
    m = mn;
  }
  const float inv = 1.f / (den + 1e-16f);
  *reinterpret_cast<float2*>(out + (size_t)dst * 128 + cofs) = make_float2(a0 * inv, a1 * inv);
}

inline int cdiv(int a, int b) { return (a + b - 1) / b; }

}  // namespace

extern "C" void kernel_launch(void* const* d_in, const int* in_sizes, int n_in,
                              void* d_out, int out_size, void* d_ws, size_t ws_size,
                              hipStream_t stream) {
  // ---- inputs (setup_inputs order) ----
  const float* x_user      = (const float*)d_in[0];
  const float* x_item      = (const float*)d_in[1];
  const int*   src_ui      = (const int*)d_in[2];
  const int*   dst_ui      = (const int*)d_in[3];
  const int*   src_iu      = (const int*)d_in[4];
  const int*   dst_iu      = (const int*)d_in[5];
  const int*   src_uu      = (const int*)d_in[6];
  const int*   dst_uu      = (const int*)d_in[7];
  const float* W_in_user   = (const float*)d_in[8];
  const float* b_in_user   = (const float*)d_in[9];
  const float* W_in_item   = (const float*)d_in[10];
  const float* b_in_item   = (const float*)d_in[11];
  const float* W_kqv_user  = (const float*)d_in[12];
  const float* b_kqv_user  = (const float*)d_in[13];
  const float* W_kqv_item  = (const float*)d_in[14];
  const float* b_kqv_item  = (const float*)d_in[15];
  const float* W_out_user  = (const float*)d_in[16];
  const float* b_out_user  = (const float*)d_in[17];
  const float* W_out_item  = (const float*)d_in[18];
  const float* b_out_item  = (const float*)d_in[19];
  const float* skip_user   = (const float*)d_in[20];
  const float* skip_item   = (const float*)d_in[21];
  const float* A_k         = (const float*)d_in[22];
  const float* A_v         = (const float*)d_in[23];
  const float* p_rel       = (const float*)d_in[24];
  const float* W_lin       = (const float*)d_in[25];
  const float* b_lin       = (const float*)d_in[26];
  float* out = (float*)d_out;
  (void)in_sizes; (void)n_in; (void)out_size; (void)ws_size;

  // ---- workspace carve-up (same proven layout as round 8) ----
  char* base = (char*)d_ws;
  size_t off = 0;
  auto alloc = [&](size_t nbytes) -> void* {
    void* p = base + off;
    off += (nbytes + 255) & ~(size_t)255;
    return p;
  };
  float* xu    = (float*)alloc((size_t)kNU * 128 * 4);   // persistent; xi contiguous after
  float* xi    = (float*)alloc((size_t)kNI * 128 * 4);
  float* tab   = (float*)alloc((size_t)15360000 * 4);    // 61.44 MB phase-overlaid
  float* agg_u = (float*)alloc((size_t)kNU * 128 * 4);
  unsigned short* TWuU   = (unsigned short*)alloc((size_t)2 * 2 * 384 * 128 * 2);
  unsigned short* TWiU   = (unsigned short*)alloc((size_t)2 * 2 * 256 * 128 * 2);
  unsigned short* TWuI   = (unsigned short*)alloc((size_t)2 * 2 * 256 * 128 * 2);
  unsigned short* TWqi   = (unsigned short*)alloc((size_t)2 * 2 * 128 * 128 * 2);
  unsigned short* TWinU  = (unsigned short*)alloc((size_t)2 * 128 * 128 * 2);
  unsigned short* TWinI  = (unsigned short*)alloc((size_t)2 * 128 * 64 * 2);
  unsigned short* TWoutU = (unsigned short*)alloc((size_t)2 * 2 * 128 * 128 * 2);
  unsigned short* TWoutI = (unsigned short*)alloc((size_t)2 * 2 * 128 * 128 * 2);
  unsigned short* TWlin  = (unsigned short*)alloc((size_t)2 * 64 * 128 * 2);
  float* buU   = (float*)alloc((size_t)2 * 384 * 4);
  float* biU   = (float*)alloc((size_t)2 * 256 * 4);
  float* buI   = (float*)alloc((size_t)2 * 256 * 4);
  int* starts_i = (int*)alloc((size_t)(kNI + 1) * 4);
  int* cursor_i = (int*)alloc((size_t)kNI * 4);
  int* list_i   = (int*)alloc((size_t)kEUI * 4);
  int* starts_u = (int*)alloc((size_t)(kNU + 1) * 4);
  int* cursor_u = (int*)alloc((size_t)kNU * 4);
  int* list_u   = (int*)alloc((size_t)kEU * 4);

  // tab overlay (float-slot offsets):
  // Phase U: q_u fp32 [NU][128] @0 | u_kv2 half [NU][256] @2.56M | i_kv half [NI][256] @5.12M
  // Phase I: u_kv0 half [NU][256] @0 | q_i fp32 [NI][128] @2.56M | agg_i fp32 [NI][128] @8.96M
  float*    q_u   = tab + 0;
  _Float16* u_kv2 = (_Float16*)(tab + 2560000);
  _Float16* i_kv  = (_Float16*)(tab + 5120000);
  _Float16* u_kv0 = (_Float16*)(tab + 0);
  float*    q_i   = tab + 2560000;
  float*    agg_i = tab + 8960000;

  // ---- CSR build (edge lists identical across layers -> once per call) ----
  zero2_kernel<<<cdiv(kNI, 256), 256, 0, stream>>>(cursor_i, kNI, cursor_u, kNU);
  count_all<<<cdiv(kEU, 256), 256, 0, stream>>>(dst_ui, dst_iu, dst_uu, cursor_i, cursor_u);
  scan2_kernel<<<2, 1024, 0, stream>>>(cursor_i, starts_i, kNI, cursor_u, starts_u, kNU);
  scatter_all<<<cdiv(kEU, 256), 256, 0, stream>>>(dst_ui, src_ui, dst_iu, src_iu,
                                                  dst_uu, src_uu, cursor_i, list_i,
                                                  cursor_u, list_u);

  // ---- weight prep (sliced across 368 blocks) ----
  build_weights<<<23 * kSlices, 256, 0, stream>>>(
      W_kqv_user, b_kqv_user, W_kqv_item, b_kqv_item, A_k, A_v, p_rel,
      W_in_user, W_in_item, W_out_user, W_out_item, W_lin,
      TWuU, TWiU, TWuI, TWqi, TWinU, TWinI, TWoutU, TWoutI, TWlin,
      buU, biU, buI);

  // ---- input projections (relu) ----
  mfma_gemm<0, 1, 0><<<dim3(1, cdiv(kNU, 128)), 256, 0, stream>>>(
      x_user, TWinU, b_in_user, xu, kNU, 128, 128, nullptr, nullptr, nullptr, 0);
  mfma_gemm<0, 1, 0><<<dim3(1, cdiv(kNI, 128)), 256, 0, stream>>>(
      x_item, TWinI, b_in_item, xi, kNI, 128, 64, nullptr, nullptr, nullptr, 0);

  for (int l = 0; l < 2; ++l) {
    // ---- phase U: [q_u fp32 | kt2|vt2 fp16] from xu; [kt1|vt1 fp16] from xi ----
    mfma_gemm<0, 0, 1><<<dim3(3, cdiv(kNU, 128)), 256, 0, stream>>>(
        xu, TWuU + (size_t)l * 2 * 384 * 128, buU + l * 384, q_u, kNU, 384, 128,
        nullptr, nullptr, u_kv2, 128);
    mfma_gemm<0, 0, 1><<<dim3(2, cdiv(kNI, 128)), 256, 0, stream>>>(
        xi, TWiU + (size_t)l * 2 * 256 * 128, biU + l * 256, nullptr, kNI, 256, 128,
        nullptr, nullptr, i_kv, 0);
    agg_wave_kernel<<<cdiv(kNU * 64, 256), 256, 0, stream>>>(
        starts_u, list_u, q_u, i_kv, u_kv2, agg_u, kNU);

    // ---- phase I: [kt0|vt0 fp16] from xu; q_i fp32 from xi ----
    mfma_gemm<0, 0, 1><<<dim3(2, cdiv(kNU, 128)), 256, 0, stream>>>(
        xu, TWuI + (size_t)l * 2 * 256 * 128, buI + l * 256, nullptr, kNU, 256, 128,
        nullptr, nullptr, u_kv0, 0);
    mfma_gemm<0, 0, 0><<<dim3(1, cdiv(kNI, 128)), 256, 0, stream>>>(
        xi, TWqi + (size_t)l * 2 * 128 * 128, b_kqv_item + (size_t)l * 384 + 128,
        q_i, kNI, 128, 128, nullptr, nullptr, nullptr, 0);
    agg_wave_kernel<<<cdiv(kNI * 64, 256), 256, 0, stream>>>(
        starts_i, list_i, q_i, u_kv0, u_kv0, agg_i, kNI);

    // ---- out-proj: gelu -> linear -> sigmoid-gated skip -> relu (in place) ----
    mfma_gemm<1, 2, 0><<<dim3(1, cdiv(kNU, 128)), 256, 0, stream>>>(
        agg_u, TWoutU + (size_t)l * 2 * 128 * 128, b_out_user + (size_t)l * 128,
        xu, kNU, 128, 128, xu, skip_user + l, nullptr, 0);
    mfma_gemm<1, 2, 0><<<dim3(1, cdiv(kNI, 128)), 256, 0, stream>>>(
        agg_i, TWoutI + (size_t)l * 2 * 128 * 128, b_out_item + (size_t)l * 128,
        xi, kNI, 128, 128, xi, skip_item + l, nullptr, 0);
  }

  // ---- final shared linear over concat([xu, xi]) (contiguous in ws) ----
  mfma_gemm<0, 0, 0><<<dim3(1, cdiv(kNU + kNI, 128)), 256, 0, stream>>>(
      xu, TWlin, b_lin, out, kNU + kNI, 64, 128, nullptr, nullptr, nullptr, 0);
}